// Round 1
// baseline (1198.194 us; speedup 1.0000x reference)
//
#include <hip/hip_runtime.h>
#include <hip/hip_bf16.h>
#include <stdint.h>
#include <stddef.h>

#define NN 50000
#define NE 800000
#define FIN 500
#define HIDN 64
#define NH 4
#define HCD 16
#define NC 8
#define SD 576            // 64 (K) + 512 (M) floats per node
#define CSTF 1e-5f

// ---------------- degree / CSR build ----------------

__global__ void k_deg(const int* __restrict__ col, int* __restrict__ deg) {
    int e = blockIdx.x * blockDim.x + threadIdx.x;
    if (e < NE) atomicAdd(&deg[col[e]], 1);
}

__global__ void k_deginv(const int* __restrict__ deg, float* __restrict__ dinv) {
    int i = blockIdx.x * blockDim.x + threadIdx.x;
    if (i < NN) dinv[i] = deg[i] > 0 ? 1.0f / (float)deg[i] : 0.0f;
}

__global__ __launch_bounds__(1024) void k_scan(const int* __restrict__ deg,
                                               int* __restrict__ offs) {
    __shared__ int sums[1024];
    int t = threadIdx.x;
    const int stripe = (NN + 1023) / 1024;     // 49
    int s0 = t * stripe;
    int s1 = min(s0 + stripe, NN);
    int tot = 0;
    for (int i = s0; i < s1; i++) tot += deg[i];
    sums[t] = tot;
    __syncthreads();
    for (int d = 1; d < 1024; d <<= 1) {
        int add = (t >= d) ? sums[t - d] : 0;
        __syncthreads();
        sums[t] += add;
        __syncthreads();
    }
    int run = (t == 0) ? 0 : sums[t - 1];
    for (int i = s0; i < s1; i++) { offs[i] = run; run += deg[i]; }
    if (t == 1023) offs[NN] = sums[1023];
}

__global__ void k_scatter(const int* __restrict__ row, const int* __restrict__ col,
                          const int* __restrict__ offs, int* __restrict__ cursor,
                          int* __restrict__ csr_src) {
    int e = blockIdx.x * blockDim.x + threadIdx.x;
    if (e < NE) {
        int c = col[e];
        int pos = offs[c] + atomicAdd(&cursor[c], 1);
        csr_src[pos] = row[e];
    }
}

// ---------------- x = relu(nf @ Wi + bi) ----------------
// Tiled: 64 nodes x 64 cols per block, K chunks of 128. Wave computes 16 nodes.

__global__ __launch_bounds__(256) void k_xgemm(const float* __restrict__ nf,
                                               const float* __restrict__ Wi,
                                               const float* __restrict__ bi,
                                               float* __restrict__ x) {
    __shared__ float wi_s[128 * 64];
    __shared__ float a_s[64 * 128];
    int t = threadIdx.x;
    int lane = t & 63;
    int w = t >> 6;
    int ntiles = (NN + 63) >> 6;
    float bv = bi[lane];
    for (int tile = blockIdx.x; tile < ntiles; tile += gridDim.x) {
        int n0 = tile << 6;
        float acc[16];
#pragma unroll
        for (int u = 0; u < 16; u++) acc[u] = 0.f;
        for (int ch = 0; ch < 4; ch++) {
            int f0 = ch << 7;
            int flen = min(128, FIN - f0);
            __syncthreads();
            for (int i = t; i < 128 * 64; i += 256) {
                int fr = i >> 6;
                wi_s[i] = (fr < flen) ? Wi[(size_t)(f0 + fr) * 64 + (i & 63)] : 0.f;
            }
            for (int i = t; i < 64 * 128; i += 256) {
                int u = i >> 7, fr = i & 127;
                int n = n0 + u;
                a_s[i] = (n < NN && fr < flen) ? nf[(size_t)n * FIN + f0 + fr] : 0.f;
            }
            __syncthreads();
            for (int fr = 0; fr < 128; fr++) {
                float wv = wi_s[fr * 64 + lane];
#pragma unroll
                for (int u = 0; u < 16; u++)
                    acc[u] = fmaf(a_s[(w * 16 + u) * 128 + fr], wv, acc[u]);
            }
        }
#pragma unroll
        for (int u = 0; u < 16; u++) {
            int n = n0 + w * 16 + u;
            if (n < NN) x[(size_t)n * 64 + lane] = fmaxf(acc[u] + bv, 0.f);
        }
    }
}

// ---------------- QKV + M outer-product + teleport sums ----------------
// Wave handles 8 nodes at a time. Lane l: Q/K col l, V col (l&31).
// S row layout: [0..63] = K, [64 + l*8 + j] = M[h=l>>4][i=l&15][j].

__global__ __launch_bounds__(256) void k_qkv(const float* __restrict__ x,
    const float* __restrict__ Wq, const float* __restrict__ bq,
    const float* __restrict__ Wk, const float* __restrict__ bk,
    const float* __restrict__ Wv, const float* __restrict__ bv,
    const float* __restrict__ hopwise,
    float* __restrict__ Qg, float* __restrict__ hid, float* __restrict__ S0,
    float* __restrict__ tMK) {
    __shared__ float wq_s[64 * 64], wk_s[64 * 64], wv_s[64 * 32];
    __shared__ float bq_s[64], bk_s[64], bv_s[32];
    __shared__ float xs[4][8][64];
    __shared__ float tacc[576];
    int t = threadIdx.x;
    for (int i = t; i < 4096; i += 256) { wq_s[i] = Wq[i]; wk_s[i] = Wk[i]; }
    for (int i = t; i < 2048; i += 256) wv_s[i] = Wv[i];
    if (t < 64) { bq_s[t] = bq[t]; bk_s[t] = bk[t]; }
    if (t >= 64 && t < 96) bv_s[t - 64] = bv[t - 64];
    for (int i = t; i < 576; i += 256) tacc[i] = 0.f;
    __syncthreads();
    int lane = t & 63;
    int w = t >> 6;
    int h = lane >> 4;
    int vcol = lane & 31;
    float hw0 = hopwise[0];
    float tkp = 0.f;
    float tmp_[8];
#pragma unroll
    for (int j = 0; j < 8; j++) tmp_[j] = 0.f;
    int tiles = (NN + 31) >> 5;
    for (int tile = blockIdx.x; tile < tiles; tile += gridDim.x) {
        int n0 = tile * 32 + w * 8;
        __syncthreads();
#pragma unroll
        for (int u = 0; u < 8; u++) {
            int n = n0 + u;
            xs[w][u][lane] = (n < NN) ? x[(size_t)n * 64 + lane] : 0.f;
        }
        __syncthreads();
        float aq[8], ak[8], av[8];
#pragma unroll
        for (int u = 0; u < 8; u++) { aq[u] = 0.f; ak[u] = 0.f; av[u] = 0.f; }
        for (int f = 0; f < 64; f++) {
            float wqv = wq_s[f * 64 + lane];
            float wkv = wk_s[f * 64 + lane];
            float wvv = wv_s[f * 32 + vcol];
#pragma unroll
            for (int u = 0; u < 8; u++) {
                float xf = xs[w][u][f];
                aq[u] = fmaf(xf, wqv, aq[u]);
                ak[u] = fmaf(xf, wkv, ak[u]);
                av[u] = fmaf(xf, wvv, av[u]);
            }
        }
#pragma unroll
        for (int u = 0; u < 8; u++) {
            int n = n0 + u;
            float q = aq[u] + bq_s[lane];
            float k = ak[u] + bk_s[lane];
            float v = av[u] + bv_s[vcol];
            float Qv = q > 0.f ? 1.f + q : expf(q);   // 1 + elu
            float Kv = k > 0.f ? 1.f + k : expf(k);
            float vj[8];
#pragma unroll
            for (int j = 0; j < 8; j++) vj[j] = __shfl(v, h * 8 + j, 64);
            if (n < NN) {
                Qg[(size_t)n * 64 + lane] = Qv;
                float* srow = S0 + (size_t)n * SD;
                srow[lane] = Kv;
                float4 m0 = make_float4(Kv * vj[0], Kv * vj[1], Kv * vj[2], Kv * vj[3]);
                float4 m1 = make_float4(Kv * vj[4], Kv * vj[5], Kv * vj[6], Kv * vj[7]);
                float4* s4 = (float4*)(srow + 64);
                s4[lane * 2] = m0;
                s4[lane * 2 + 1] = m1;
                if (lane < 32) hid[(size_t)n * 32 + lane] = v * hw0;
                tkp += Kv;
                tmp_[0] += m0.x; tmp_[1] += m0.y; tmp_[2] += m0.z; tmp_[3] += m0.w;
                tmp_[4] += m1.x; tmp_[5] += m1.y; tmp_[6] += m1.z; tmp_[7] += m1.w;
            }
        }
    }
#pragma unroll
    for (int j = 0; j < 8; j++) atomicAdd(&tacc[lane * 8 + j], tmp_[j]);
    atomicAdd(&tacc[512 + lane], tkp);
    __syncthreads();
    for (int i = t; i < 576; i += 256) atomicAdd(&tMK[i], tacc[i]);
}

// ---------------- propagate one hop + fused attend ----------------
// One wave per destination node. Lane l accumulates K[l] and M[l*8 .. l*8+7].

__global__ __launch_bounds__(256) void k_prop(const float* __restrict__ Sold,
    const int* __restrict__ offs, const int* __restrict__ csr_src,
    const float* __restrict__ dinv, const float* __restrict__ Qg,
    const float* __restrict__ hopwise, const float* __restrict__ headwise,
    int hop, int writeS, float* __restrict__ Snew, float* __restrict__ hid) {
    int t = threadIdx.x;
    int lane = t & 63;
    int n = (blockIdx.x * 256 + t) >> 6;
    if (n >= NN) return;
    int h = lane >> 4;
    float e0 = expf(headwise[0 * 2 + hop]);
    float e1 = expf(headwise[1 * 2 + hop]);
    float e2 = expf(headwise[2 * 2 + hop]);
    float e3 = expf(headwise[3 * 2 + hop]);
    float esum = e0 + e1 + e2 + e3;
    float eh = (h == 0) ? e0 : ((h == 1) ? e1 : ((h == 2) ? e2 : e3));
    float gam = hopwise[hop + 1] * eh / esum;

    int o0 = offs[n], o1 = offs[n + 1];
    float kacc = 0.f;
    float4 m0 = make_float4(0.f, 0.f, 0.f, 0.f);
    float4 m1 = make_float4(0.f, 0.f, 0.f, 0.f);
    for (int e = o0; e < o1; e++) {
        int src = csr_src[e];
        float wgt = dinv[src];
        const float* srow = Sold + (size_t)src * SD;
        kacc = fmaf(wgt, srow[lane], kacc);
        const float4* s4 = (const float4*)(srow + 64);
        float4 a = s4[lane * 2];
        float4 b = s4[lane * 2 + 1];
        m0.x = fmaf(wgt, a.x, m0.x); m0.y = fmaf(wgt, a.y, m0.y);
        m0.z = fmaf(wgt, a.z, m0.z); m0.w = fmaf(wgt, a.w, m0.w);
        m1.x = fmaf(wgt, b.x, m1.x); m1.y = fmaf(wgt, b.y, m1.y);
        m1.z = fmaf(wgt, b.z, m1.z); m1.w = fmaf(wgt, b.w, m1.w);
    }
    if (writeS) {
        float* drow = Snew + (size_t)n * SD;
        drow[lane] = kacc;
        float4* d4 = (float4*)(drow + 64);
        d4[lane * 2] = m0;
        d4[lane * 2 + 1] = m1;
    }
    // attend: Hh[h][j] = sum_i Q[h][i]*M[h][i][j]; Cc[h] = sum_i Q[h][i]*K[h][i]
    float qv = Qg[(size_t)n * 64 + lane];
    float hh[8];
    hh[0] = qv * m0.x; hh[1] = qv * m0.y; hh[2] = qv * m0.z; hh[3] = qv * m0.w;
    hh[4] = qv * m1.x; hh[5] = qv * m1.y; hh[6] = qv * m1.z; hh[7] = qv * m1.w;
    float cc = qv * kacc;
#pragma unroll
    for (int s = 1; s < 16; s <<= 1) {
#pragma unroll
        for (int j = 0; j < 8; j++) hh[j] += __shfl_xor(hh[j], s, 16);
        cc += __shfl_xor(cc, s, 16);
    }
    if ((lane & 15) < 8) {
        int j = lane & 7;
        float val = j < 4 ? (j < 2 ? (j == 0 ? hh[0] : hh[1]) : (j == 2 ? hh[2] : hh[3]))
                          : (j < 6 ? (j == 4 ? hh[4] : hh[5]) : (j == 6 ? hh[6] : hh[7]));
        size_t idx = (size_t)n * 32 + h * 8 + j;
        hid[idx] += gam * val / (cc + CSTF);
    }
}

// ---------------- final: out = hidden @ Wo + bo + teleport * teleportH ----------------
// 8 lanes per node (lane&7 = class), 8 nodes per wave.

__global__ __launch_bounds__(256) void k_final(const float* __restrict__ hid,
    const float* __restrict__ Qg, const float* __restrict__ Wo,
    const float* __restrict__ bo, const float* __restrict__ tMK,
    const float* __restrict__ teleport, float* __restrict__ out) {
    __shared__ float tm[512];
    __shared__ float tk[64];
    __shared__ float wo[256];
    __shared__ float bos[8];
    int t = threadIdx.x;
    const float invN = 1.0f / (float)NN;
    for (int i = t; i < 512; i += 256) tm[i] = tMK[i] * invN;
    if (t < 64) tk[t] = tMK[512 + t] * invN;
    wo[t] = Wo[t & 255];   // 256 threads load 256 Wo entries
    if (t < 8) bos[t] = bo[t];
    __syncthreads();
    float tp = teleport[0];
    int lane = t & 63;
    int sub = lane & 7;
    int g = lane >> 3;
    int wid = (blockIdx.x * 256 + t) >> 6;
    int nwaves = gridDim.x * 4;
    for (int nb = wid * 8; nb < NN; nb += nwaves * 8) {
        int n = nb + g;
        if (n < NN) {
            const float* hrow = hid + (size_t)n * 32;
            const float* qrow = Qg + (size_t)n * 64;
            float o = bos[sub];
#pragma unroll
            for (int m = 0; m < 32; m++) o = fmaf(hrow[m], wo[m * 8 + sub], o);
            float th = 0.f;
#pragma unroll
            for (int h2 = 0; h2 < 4; h2++) {
                float num = 0.f, den = 0.f;
#pragma unroll
                for (int i = 0; i < 16; i++) {
                    float q = qrow[h2 * 16 + i];
                    num = fmaf(q, tm[h2 * 128 + i * 8 + sub], num);
                    den = fmaf(q, tk[h2 * 16 + i], den);
                }
                th += num / (den + CSTF);
            }
            out[(size_t)n * 8 + sub] = o + tp * th;
        }
    }
}

// ---------------- launch ----------------

extern "C" void kernel_launch(void* const* d_in, const int* in_sizes, int n_in,
                              void* d_out, int out_size, void* d_ws, size_t ws_size,
                              hipStream_t stream) {
    const float* nf = (const float*)d_in[0];
    const int* ei = (const int*)d_in[1];
    const float* Wi = (const float*)d_in[2];
    const float* bi = (const float*)d_in[3];
    const float* Wq = (const float*)d_in[4];
    const float* bq = (const float*)d_in[5];
    const float* Wk = (const float*)d_in[6];
    const float* bk = (const float*)d_in[7];
    const float* Wv = (const float*)d_in[8];
    const float* bv = (const float*)d_in[9];
    const float* Wo = (const float*)d_in[10];
    const float* bo = (const float*)d_in[11];
    const float* hopwise = (const float*)d_in[12];
    const float* headwise = (const float*)d_in[13];
    const float* teleport = (const float*)d_in[14];
    float* out = (float*)d_out;

    char* base = (char*)d_ws;
    size_t off = 0;
    auto alloc = [&](size_t bytes) -> void* {
        void* p = base + off;
        off = (off + bytes + 255) & ~(size_t)255;
        return p;
    };
    int* deg = (int*)alloc(NN * 4);
    int* cursor = (int*)alloc(NN * 4);
    int* offs = (int*)alloc((NN + 1) * 4);
    float* dinv = (float*)alloc(NN * 4);
    int* csr_src = (int*)alloc((size_t)NE * 4);
    float* xbuf = (float*)alloc((size_t)NN * 64 * 4);
    float* Qg = (float*)alloc((size_t)NN * 64 * 4);
    float* hid = (float*)alloc((size_t)NN * 32 * 4);
    float* Sa = (float*)alloc((size_t)NN * SD * 4);
    float* Sb = (float*)alloc((size_t)NN * SD * 4);
    float* tMK = (float*)alloc(576 * 4);

    const int* rowp = ei;
    const int* colp = ei + NE;

    hipMemsetAsync(deg, 0, NN * 4, stream);
    hipMemsetAsync(cursor, 0, NN * 4, stream);
    hipMemsetAsync(tMK, 0, 576 * 4, stream);

    k_deg<<<(NE + 255) / 256, 256, 0, stream>>>(colp, deg);
    k_deginv<<<(NN + 255) / 256, 256, 0, stream>>>(deg, dinv);
    k_scan<<<1, 1024, 0, stream>>>(deg, offs);
    k_scatter<<<(NE + 255) / 256, 256, 0, stream>>>(rowp, colp, offs, cursor, csr_src);
    k_xgemm<<<782, 256, 0, stream>>>(nf, Wi, bi, xbuf);
    k_qkv<<<512, 256, 0, stream>>>(xbuf, Wq, bq, Wk, bk, Wv, bv, hopwise,
                                   Qg, hid, Sa, tMK);
    k_prop<<<(NN * 64 + 255) / 256, 256, 0, stream>>>(Sa, offs, csr_src, dinv, Qg,
                                                      hopwise, headwise, 0, 1, Sb, hid);
    k_prop<<<(NN * 64 + 255) / 256, 256, 0, stream>>>(Sb, offs, csr_src, dinv, Qg,
                                                      hopwise, headwise, 1, 0, Sb, hid);
    k_final<<<1563, 256, 0, stream>>>(hid, Qg, Wo, bo, tMK, teleport, out);
}

// Round 2
// 950.714 us; speedup vs baseline: 1.2603x; 1.2603x over previous
//
#include <hip/hip_runtime.h>
#include <hip/hip_bf16.h>
#include <stdint.h>
#include <stddef.h>

#define NN 50000
#define NE 800000
#define FIN 500
#define HIDN 64
#define NH 4
#define HCD 16
#define NC 8
#define SD 576            // 64 (K) + 512 (M) floats per node
#define CSTF 1e-5f

// ---------------- degree / CSR build ----------------

__global__ void k_deg(const int* __restrict__ col, int* __restrict__ deg) {
    int e = blockIdx.x * blockDim.x + threadIdx.x;
    if (e < NE) atomicAdd(&deg[col[e]], 1);
}

__global__ void k_deginv(const int* __restrict__ deg, float* __restrict__ dinv) {
    int i = blockIdx.x * blockDim.x + threadIdx.x;
    if (i < NN) dinv[i] = deg[i] > 0 ? 1.0f / (float)deg[i] : 0.0f;
}

__global__ __launch_bounds__(1024) void k_scan(const int* __restrict__ deg,
                                               int* __restrict__ offs) {
    __shared__ int sums[1024];
    int t = threadIdx.x;
    const int stripe = (NN + 1023) / 1024;     // 49
    int s0 = t * stripe;
    int s1 = min(s0 + stripe, NN);
    int tot = 0;
    for (int i = s0; i < s1; i++) tot += deg[i];
    sums[t] = tot;
    __syncthreads();
    for (int d = 1; d < 1024; d <<= 1) {
        int add = (t >= d) ? sums[t - d] : 0;
        __syncthreads();
        sums[t] += add;
        __syncthreads();
    }
    int run = (t == 0) ? 0 : sums[t - 1];
    for (int i = s0; i < s1; i++) { offs[i] = run; run += deg[i]; }
    if (t == 1023) offs[NN] = sums[1023];
}

__global__ void k_scatter(const int* __restrict__ row, const int* __restrict__ col,
                          const int* __restrict__ offs, int* __restrict__ cursor,
                          int* __restrict__ csr_src) {
    int e = blockIdx.x * blockDim.x + threadIdx.x;
    if (e < NE) {
        int c = col[e];
        int pos = offs[c] + atomicAdd(&cursor[c], 1);
        csr_src[pos] = row[e];
    }
}

// ---------------- x = relu(nf @ Wi + bi) ----------------
// Register-tiled: 64 rows x 64 cols per block, TK=32 (K padded to 512).
// 256 threads; thread = (rg = t>>4 -> rows 4rg..4rg+3, cg = t&15 -> cols 4cg..4cg+3).
// Per 4-k step: 4 float4 A reads + 4 float4 W reads -> 64 FMA (8 FMA / ds_read_b128).

#define XG_TK 32
#define XG_AS 36   // a_s row stride (pad 32->36, keeps 16B alignment, breaks bank collide)

__global__ __launch_bounds__(256) void k_xgemm(const float* __restrict__ nf,
                                               const float* __restrict__ Wi,
                                               const float* __restrict__ bi,
                                               float* __restrict__ x) {
    __shared__ __align__(16) float a_s[64 * XG_AS];
    __shared__ __align__(16) float w_s[XG_TK * 64];
    int t = threadIdx.x;
    int cg = t & 15;          // col group: cols 4cg..4cg+3
    int rg = t >> 4;          // row group: rows 4rg..4rg+3
    int c0 = cg * 4;
    int n0 = blockIdx.x * 64;

    // staging maps
    int a_f4 = t & 7;         // float4 index within row (k = 16B*a_f4)
    int a_row = t >> 3;       // rows 0..31, +32 second pass
    int w_c4 = (t & 15) * 4;  // col
    int w_k = t >> 4;         // k rows 0..15, +16 second pass

    float4 acc[4];
#pragma unroll
    for (int r = 0; r < 4; r++) acc[r] = make_float4(0.f, 0.f, 0.f, 0.f);

    for (int k0 = 0; k0 < FIN; k0 += XG_TK) {
        __syncthreads();
        // stage A: 64 rows x 32 k
#pragma unroll
        for (int p = 0; p < 2; p++) {
            int row = a_row + p * 32;
            int n = n0 + row;
            int kk = k0 + a_f4 * 4;
            float4 v = make_float4(0.f, 0.f, 0.f, 0.f);
            if (n < NN && kk < FIN)
                v = *(const float4*)&nf[(size_t)n * FIN + kk];
            *(float4*)&a_s[row * XG_AS + a_f4 * 4] = v;
        }
        // stage W: 32 k x 64 c (k-major)
#pragma unroll
        for (int p = 0; p < 2; p++) {
            int kk = w_k + p * 16;
            float4 v = make_float4(0.f, 0.f, 0.f, 0.f);
            if (k0 + kk < FIN)
                v = *(const float4*)&Wi[(size_t)(k0 + kk) * 64 + w_c4];
            *(float4*)&w_s[kk * 64 + w_c4] = v;
        }
        __syncthreads();
#pragma unroll 2
        for (int kk = 0; kk < XG_TK; kk += 4) {
            float4 av[4];
#pragma unroll
            for (int r = 0; r < 4; r++)
                av[r] = *(const float4*)&a_s[(rg * 4 + r) * XG_AS + kk];
#pragma unroll
            for (int j = 0; j < 4; j++) {
                float4 wv = *(const float4*)&w_s[(kk + j) * 64 + c0];
#pragma unroll
                for (int r = 0; r < 4; r++) {
                    float a = (j == 0) ? av[r].x : (j == 1) ? av[r].y
                             : (j == 2) ? av[r].z : av[r].w;
                    acc[r].x = fmaf(a, wv.x, acc[r].x);
                    acc[r].y = fmaf(a, wv.y, acc[r].y);
                    acc[r].z = fmaf(a, wv.z, acc[r].z);
                    acc[r].w = fmaf(a, wv.w, acc[r].w);
                }
            }
        }
    }
    float4 b4 = *(const float4*)&bi[c0];
#pragma unroll
    for (int r = 0; r < 4; r++) {
        int n = n0 + rg * 4 + r;
        if (n < NN) {
            float4 o;
            o.x = fmaxf(acc[r].x + b4.x, 0.f);
            o.y = fmaxf(acc[r].y + b4.y, 0.f);
            o.z = fmaxf(acc[r].z + b4.z, 0.f);
            o.w = fmaxf(acc[r].w + b4.w, 0.f);
            *(float4*)&x[(size_t)n * 64 + c0] = o;
        }
    }
}

// ---------------- QKV + M outer-product + teleport sums ----------------
// Wave handles 8 nodes at a time. Lane l: Q/K col l, V col (l&31).
// S row layout: [0..63] = K, [64 + l*8 + j] = M[h=l>>4][i=l&15][j].

__global__ __launch_bounds__(256) void k_qkv(const float* __restrict__ x,
    const float* __restrict__ Wq, const float* __restrict__ bq,
    const float* __restrict__ Wk, const float* __restrict__ bk,
    const float* __restrict__ Wv, const float* __restrict__ bv,
    const float* __restrict__ hopwise,
    float* __restrict__ Qg, float* __restrict__ hid, float* __restrict__ S0,
    float* __restrict__ tMK) {
    __shared__ float wq_s[64 * 64], wk_s[64 * 64], wv_s[64 * 32];
    __shared__ float bq_s[64], bk_s[64], bv_s[32];
    __shared__ float xs[4][8][64];
    __shared__ float tacc[576];
    int t = threadIdx.x;
    for (int i = t; i < 4096; i += 256) { wq_s[i] = Wq[i]; wk_s[i] = Wk[i]; }
    for (int i = t; i < 2048; i += 256) wv_s[i] = Wv[i];
    if (t < 64) { bq_s[t] = bq[t]; bk_s[t] = bk[t]; }
    if (t >= 64 && t < 96) bv_s[t - 64] = bv[t - 64];
    for (int i = t; i < 576; i += 256) tacc[i] = 0.f;
    __syncthreads();
    int lane = t & 63;
    int w = t >> 6;
    int h = lane >> 4;
    int vcol = lane & 31;
    float hw0 = hopwise[0];
    float tkp = 0.f;
    float tmp_[8];
#pragma unroll
    for (int j = 0; j < 8; j++) tmp_[j] = 0.f;
    int tiles = (NN + 31) >> 5;
    for (int tile = blockIdx.x; tile < tiles; tile += gridDim.x) {
        int n0 = tile * 32 + w * 8;
        __syncthreads();
#pragma unroll
        for (int u = 0; u < 8; u++) {
            int n = n0 + u;
            xs[w][u][lane] = (n < NN) ? x[(size_t)n * 64 + lane] : 0.f;
        }
        __syncthreads();
        float aq[8], ak[8], av[8];
#pragma unroll
        for (int u = 0; u < 8; u++) { aq[u] = 0.f; ak[u] = 0.f; av[u] = 0.f; }
        for (int f = 0; f < 64; f++) {
            float wqv = wq_s[f * 64 + lane];
            float wkv = wk_s[f * 64 + lane];
            float wvv = wv_s[f * 32 + vcol];
#pragma unroll
            for (int u = 0; u < 8; u++) {
                float xf = xs[w][u][f];
                aq[u] = fmaf(xf, wqv, aq[u]);
                ak[u] = fmaf(xf, wkv, ak[u]);
                av[u] = fmaf(xf, wvv, av[u]);
            }
        }
#pragma unroll
        for (int u = 0; u < 8; u++) {
            int n = n0 + u;
            float q = aq[u] + bq_s[lane];
            float k = ak[u] + bk_s[lane];
            float v = av[u] + bv_s[vcol];
            float Qv = q > 0.f ? 1.f + q : expf(q);   // 1 + elu
            float Kv = k > 0.f ? 1.f + k : expf(k);
            float vj[8];
#pragma unroll
            for (int j = 0; j < 8; j++) vj[j] = __shfl(v, h * 8 + j, 64);
            if (n < NN) {
                Qg[(size_t)n * 64 + lane] = Qv;
                float* srow = S0 + (size_t)n * SD;
                srow[lane] = Kv;
                float4 m0 = make_float4(Kv * vj[0], Kv * vj[1], Kv * vj[2], Kv * vj[3]);
                float4 m1 = make_float4(Kv * vj[4], Kv * vj[5], Kv * vj[6], Kv * vj[7]);
                float4* s4 = (float4*)(srow + 64);
                s4[lane * 2] = m0;
                s4[lane * 2 + 1] = m1;
                if (lane < 32) hid[(size_t)n * 32 + lane] = v * hw0;
                tkp += Kv;
                tmp_[0] += m0.x; tmp_[1] += m0.y; tmp_[2] += m0.z; tmp_[3] += m0.w;
                tmp_[4] += m1.x; tmp_[5] += m1.y; tmp_[6] += m1.z; tmp_[7] += m1.w;
            }
        }
    }
#pragma unroll
    for (int j = 0; j < 8; j++) atomicAdd(&tacc[lane * 8 + j], tmp_[j]);
    atomicAdd(&tacc[512 + lane], tkp);
    __syncthreads();
    for (int i = t; i < 576; i += 256) atomicAdd(&tMK[i], tacc[i]);
}

// ---------------- propagate one hop + fused attend ----------------
// One wave per destination node. Lane l accumulates K[l] and M[l*8 .. l*8+7].

__global__ __launch_bounds__(256) void k_prop(const float* __restrict__ Sold,
    const int* __restrict__ offs, const int* __restrict__ csr_src,
    const float* __restrict__ dinv, const float* __restrict__ Qg,
    const float* __restrict__ hopwise, const float* __restrict__ headwise,
    int hop, int writeS, float* __restrict__ Snew, float* __restrict__ hid) {
    int t = threadIdx.x;
    int lane = t & 63;
    int n = (blockIdx.x * 256 + t) >> 6;
    if (n >= NN) return;
    int h = lane >> 4;
    float e0 = expf(headwise[0 * 2 + hop]);
    float e1 = expf(headwise[1 * 2 + hop]);
    float e2 = expf(headwise[2 * 2 + hop]);
    float e3 = expf(headwise[3 * 2 + hop]);
    float esum = e0 + e1 + e2 + e3;
    float eh = (h == 0) ? e0 : ((h == 1) ? e1 : ((h == 2) ? e2 : e3));
    float gam = hopwise[hop + 1] * eh / esum;

    int o0 = offs[n], o1 = offs[n + 1];
    float kacc = 0.f;
    float4 m0 = make_float4(0.f, 0.f, 0.f, 0.f);
    float4 m1 = make_float4(0.f, 0.f, 0.f, 0.f);
    for (int e = o0; e < o1; e++) {
        int src = csr_src[e];
        float wgt = dinv[src];
        const float* srow = Sold + (size_t)src * SD;
        kacc = fmaf(wgt, srow[lane], kacc);
        const float4* s4 = (const float4*)(srow + 64);
        float4 a = s4[lane * 2];
        float4 b = s4[lane * 2 + 1];
        m0.x = fmaf(wgt, a.x, m0.x); m0.y = fmaf(wgt, a.y, m0.y);
        m0.z = fmaf(wgt, a.z, m0.z); m0.w = fmaf(wgt, a.w, m0.w);
        m1.x = fmaf(wgt, b.x, m1.x); m1.y = fmaf(wgt, b.y, m1.y);
        m1.z = fmaf(wgt, b.z, m1.z); m1.w = fmaf(wgt, b.w, m1.w);
    }
    if (writeS) {
        float* drow = Snew + (size_t)n * SD;
        drow[lane] = kacc;
        float4* d4 = (float4*)(drow + 64);
        d4[lane * 2] = m0;
        d4[lane * 2 + 1] = m1;
    }
    // attend: Hh[h][j] = sum_i Q[h][i]*M[h][i][j]; Cc[h] = sum_i Q[h][i]*K[h][i]
    float qv = Qg[(size_t)n * 64 + lane];
    float hh[8];
    hh[0] = qv * m0.x; hh[1] = qv * m0.y; hh[2] = qv * m0.z; hh[3] = qv * m0.w;
    hh[4] = qv * m1.x; hh[5] = qv * m1.y; hh[6] = qv * m1.z; hh[7] = qv * m1.w;
    float cc = qv * kacc;
#pragma unroll
    for (int s = 1; s < 16; s <<= 1) {
#pragma unroll
        for (int j = 0; j < 8; j++) hh[j] += __shfl_xor(hh[j], s, 16);
        cc += __shfl_xor(cc, s, 16);
    }
    if ((lane & 15) < 8) {
        int j = lane & 7;
        float val = j < 4 ? (j < 2 ? (j == 0 ? hh[0] : hh[1]) : (j == 2 ? hh[2] : hh[3]))
                          : (j < 6 ? (j == 4 ? hh[4] : hh[5]) : (j == 6 ? hh[6] : hh[7]));
        size_t idx = (size_t)n * 32 + h * 8 + j;
        hid[idx] += gam * val / (cc + CSTF);
    }
}

// ---------------- final: out = hidden @ Wo + bo + teleport * teleportH ----------------
// 8 lanes per node (lane&7 = class), 8 nodes per wave.

__global__ __launch_bounds__(256) void k_final(const float* __restrict__ hid,
    const float* __restrict__ Qg, const float* __restrict__ Wo,
    const float* __restrict__ bo, const float* __restrict__ tMK,
    const float* __restrict__ teleport, float* __restrict__ out) {
    __shared__ float tm[512];
    __shared__ float tk[64];
    __shared__ float wo[256];
    __shared__ float bos[8];
    int t = threadIdx.x;
    const float invN = 1.0f / (float)NN;
    for (int i = t; i < 512; i += 256) tm[i] = tMK[i] * invN;
    if (t < 64) tk[t] = tMK[512 + t] * invN;
    wo[t] = Wo[t & 255];   // 256 threads load 256 Wo entries
    if (t < 8) bos[t] = bo[t];
    __syncthreads();
    float tp = teleport[0];
    int lane = t & 63;
    int sub = lane & 7;
    int g = lane >> 3;
    int wid = (blockIdx.x * 256 + t) >> 6;
    int nwaves = gridDim.x * 4;
    for (int nb = wid * 8; nb < NN; nb += nwaves * 8) {
        int n = nb + g;
        if (n < NN) {
            const float* hrow = hid + (size_t)n * 32;
            const float* qrow = Qg + (size_t)n * 64;
            float o = bos[sub];
#pragma unroll
            for (int m = 0; m < 32; m++) o = fmaf(hrow[m], wo[m * 8 + sub], o);
            float th = 0.f;
#pragma unroll
            for (int h2 = 0; h2 < 4; h2++) {
                float num = 0.f, den = 0.f;
#pragma unroll
                for (int i = 0; i < 16; i++) {
                    float q = qrow[h2 * 16 + i];
                    num = fmaf(q, tm[h2 * 128 + i * 8 + sub], num);
                    den = fmaf(q, tk[h2 * 16 + i], den);
                }
                th += num / (den + CSTF);
            }
            out[(size_t)n * 8 + sub] = o + tp * th;
        }
    }
}

// ---------------- launch ----------------

extern "C" void kernel_launch(void* const* d_in, const int* in_sizes, int n_in,
                              void* d_out, int out_size, void* d_ws, size_t ws_size,
                              hipStream_t stream) {
    const float* nf = (const float*)d_in[0];
    const int* ei = (const int*)d_in[1];
    const float* Wi = (const float*)d_in[2];
    const float* bi = (const float*)d_in[3];
    const float* Wq = (const float*)d_in[4];
    const float* bq = (const float*)d_in[5];
    const float* Wk = (const float*)d_in[6];
    const float* bk = (const float*)d_in[7];
    const float* Wv = (const float*)d_in[8];
    const float* bv = (const float*)d_in[9];
    const float* Wo = (const float*)d_in[10];
    const float* bo = (const float*)d_in[11];
    const float* hopwise = (const float*)d_in[12];
    const float* headwise = (const float*)d_in[13];
    const float* teleport = (const float*)d_in[14];
    float* out = (float*)d_out;

    char* base = (char*)d_ws;
    size_t off = 0;
    auto alloc = [&](size_t bytes) -> void* {
        void* p = base + off;
        off = (off + bytes + 255) & ~(size_t)255;
        return p;
    };
    int* deg = (int*)alloc(NN * 4);
    int* cursor = (int*)alloc(NN * 4);
    int* offs = (int*)alloc((NN + 1) * 4);
    float* dinv = (float*)alloc(NN * 4);
    int* csr_src = (int*)alloc((size_t)NE * 4);
    float* xbuf = (float*)alloc((size_t)NN * 64 * 4);
    float* Qg = (float*)alloc((size_t)NN * 64 * 4);
    float* hid = (float*)alloc((size_t)NN * 32 * 4);
    float* Sa = (float*)alloc((size_t)NN * SD * 4);
    float* Sb = (float*)alloc((size_t)NN * SD * 4);
    float* tMK = (float*)alloc(576 * 4);

    const int* rowp = ei;
    const int* colp = ei + NE;

    hipMemsetAsync(deg, 0, NN * 4, stream);
    hipMemsetAsync(cursor, 0, NN * 4, stream);
    hipMemsetAsync(tMK, 0, 576 * 4, stream);

    k_deg<<<(NE + 255) / 256, 256, 0, stream>>>(colp, deg);
    k_deginv<<<(NN + 255) / 256, 256, 0, stream>>>(deg, dinv);
    k_scan<<<1, 1024, 0, stream>>>(deg, offs);
    k_scatter<<<(NE + 255) / 256, 256, 0, stream>>>(rowp, colp, offs, cursor, csr_src);
    k_xgemm<<<(NN + 63) / 64, 256, 0, stream>>>(nf, Wi, bi, xbuf);
    k_qkv<<<512, 256, 0, stream>>>(xbuf, Wq, bq, Wk, bk, Wv, bv, hopwise,
                                   Qg, hid, Sa, tMK);
    k_prop<<<(NN * 64 + 255) / 256, 256, 0, stream>>>(Sa, offs, csr_src, dinv, Qg,
                                                      hopwise, headwise, 0, 1, Sb, hid);
    k_prop<<<(NN * 64 + 255) / 256, 256, 0, stream>>>(Sb, offs, csr_src, dinv, Qg,
                                                      hopwise, headwise, 1, 0, Sb, hid);
    k_final<<<1563, 256, 0, stream>>>(hid, Qg, Wo, bo, tMK, teleport, out);
}

// Round 3
// 699.760 us; speedup vs baseline: 1.7123x; 1.3586x over previous
//
#include <hip/hip_runtime.h>
#include <hip/hip_bf16.h>
#include <stdint.h>
#include <stddef.h>

#define NN 50000
#define NE 800000
#define FIN 500
#define HIDN 64
#define NH 4
#define HCD 16
#define NC 8
#define SD 576            // 64 (K) + 512 (M) bf16 per node (1152 B row)
#define CSTF 1e-5f

// bf16 helpers (storage-only; all math fp32)
__device__ inline float bf_lo(unsigned u) {
    union { unsigned i; float f; } v; v.i = u << 16; return v.f;
}
__device__ inline float bf_hi(unsigned u) {
    union { unsigned i; float f; } v; v.i = u & 0xffff0000u; return v.f;
}
__device__ inline unsigned short f2bf(float f) {
    union { float f; unsigned i; } v; v.f = f;
    unsigned r = v.i + 0x7fffu + ((v.i >> 16) & 1u);   // RNE
    return (unsigned short)(r >> 16);
}
__device__ inline unsigned packbf(float a, float b) {
    return (unsigned)f2bf(a) | ((unsigned)f2bf(b) << 16);
}

// ---------------- degree / CSR build ----------------

__global__ void k_deg(const int* __restrict__ col, int* __restrict__ deg) {
    int e = blockIdx.x * blockDim.x + threadIdx.x;
    if (e < NE) atomicAdd(&deg[col[e]], 1);
}

__global__ void k_deginv(const int* __restrict__ deg, float* __restrict__ dinv) {
    int i = blockIdx.x * blockDim.x + threadIdx.x;
    if (i < NN) dinv[i] = deg[i] > 0 ? 1.0f / (float)deg[i] : 0.0f;
}

__global__ __launch_bounds__(1024) void k_scan(const int* __restrict__ deg,
                                               int* __restrict__ offs) {
    __shared__ int sums[1024];
    int t = threadIdx.x;
    const int stripe = (NN + 1023) / 1024;     // 49
    int s0 = t * stripe;
    int s1 = min(s0 + stripe, NN);
    int tot = 0;
    for (int i = s0; i < s1; i++) tot += deg[i];
    sums[t] = tot;
    __syncthreads();
    for (int d = 1; d < 1024; d <<= 1) {
        int add = (t >= d) ? sums[t - d] : 0;
        __syncthreads();
        sums[t] += add;
        __syncthreads();
    }
    int run = (t == 0) ? 0 : sums[t - 1];
    for (int i = s0; i < s1; i++) { offs[i] = run; run += deg[i]; }
    if (t == 1023) offs[NN] = sums[1023];
}

__global__ void k_scatter(const int* __restrict__ row, const int* __restrict__ col,
                          const int* __restrict__ offs, int* __restrict__ cursor,
                          int* __restrict__ csr_src) {
    int e = blockIdx.x * blockDim.x + threadIdx.x;
    if (e < NE) {
        int c = col[e];
        int pos = offs[c] + atomicAdd(&cursor[c], 1);
        csr_src[pos] = row[e];
    }
}

// ---------------- x = relu(nf @ Wi + bi) ----------------

#define XG_TK 32
#define XG_AS 36

__global__ __launch_bounds__(256) void k_xgemm(const float* __restrict__ nf,
                                               const float* __restrict__ Wi,
                                               const float* __restrict__ bi,
                                               float* __restrict__ x) {
    __shared__ __align__(16) float a_s[64 * XG_AS];
    __shared__ __align__(16) float w_s[XG_TK * 64];
    int t = threadIdx.x;
    int cg = t & 15;
    int rg = t >> 4;
    int c0 = cg * 4;
    int n0 = blockIdx.x * 64;

    int a_f4 = t & 7;
    int a_row = t >> 3;
    int w_c4 = (t & 15) * 4;
    int w_k = t >> 4;

    float4 acc[4];
#pragma unroll
    for (int r = 0; r < 4; r++) acc[r] = make_float4(0.f, 0.f, 0.f, 0.f);

    for (int k0 = 0; k0 < FIN; k0 += XG_TK) {
        __syncthreads();
#pragma unroll
        for (int p = 0; p < 2; p++) {
            int row = a_row + p * 32;
            int n = n0 + row;
            int kk = k0 + a_f4 * 4;
            float4 v = make_float4(0.f, 0.f, 0.f, 0.f);
            if (n < NN && kk < FIN)
                v = *(const float4*)&nf[(size_t)n * FIN + kk];
            *(float4*)&a_s[row * XG_AS + a_f4 * 4] = v;
        }
#pragma unroll
        for (int p = 0; p < 2; p++) {
            int kk = w_k + p * 16;
            float4 v = make_float4(0.f, 0.f, 0.f, 0.f);
            if (k0 + kk < FIN)
                v = *(const float4*)&Wi[(size_t)(k0 + kk) * 64 + w_c4];
            *(float4*)&w_s[kk * 64 + w_c4] = v;
        }
        __syncthreads();
#pragma unroll 2
        for (int kk = 0; kk < XG_TK; kk += 4) {
            float4 av[4];
#pragma unroll
            for (int r = 0; r < 4; r++)
                av[r] = *(const float4*)&a_s[(rg * 4 + r) * XG_AS + kk];
#pragma unroll
            for (int j = 0; j < 4; j++) {
                float4 wv = *(const float4*)&w_s[(kk + j) * 64 + c0];
#pragma unroll
                for (int r = 0; r < 4; r++) {
                    float a = (j == 0) ? av[r].x : (j == 1) ? av[r].y
                             : (j == 2) ? av[r].z : av[r].w;
                    acc[r].x = fmaf(a, wv.x, acc[r].x);
                    acc[r].y = fmaf(a, wv.y, acc[r].y);
                    acc[r].z = fmaf(a, wv.z, acc[r].z);
                    acc[r].w = fmaf(a, wv.w, acc[r].w);
                }
            }
        }
    }
    float4 b4 = *(const float4*)&bi[c0];
#pragma unroll
    for (int r = 0; r < 4; r++) {
        int n = n0 + rg * 4 + r;
        if (n < NN) {
            float4 o;
            o.x = fmaxf(acc[r].x + b4.x, 0.f);
            o.y = fmaxf(acc[r].y + b4.y, 0.f);
            o.z = fmaxf(acc[r].z + b4.z, 0.f);
            o.w = fmaxf(acc[r].w + b4.w, 0.f);
            *(float4*)&x[(size_t)n * 64 + c0] = o;
        }
    }
}

// ---------------- QKV + M outer-product + teleport sums ----------------
// S row (bf16): [0..63] = K*dinv, [64 + l*8 + j] = M[h=l>>4][i=l&15][j]*dinv.
// dinv folded at store so k_prop needs no per-edge dinv lookup.

__global__ __launch_bounds__(256) void k_qkv(const float* __restrict__ x,
    const float* __restrict__ Wq, const float* __restrict__ bq,
    const float* __restrict__ Wk, const float* __restrict__ bk,
    const float* __restrict__ Wv, const float* __restrict__ bv,
    const float* __restrict__ hopwise, const float* __restrict__ dinv,
    float* __restrict__ Qg, float* __restrict__ hid,
    unsigned short* __restrict__ S0, float* __restrict__ tMK) {
    __shared__ float wq_s[64 * 64], wk_s[64 * 64], wv_s[64 * 32];
    __shared__ float bq_s[64], bk_s[64], bv_s[32];
    __shared__ float xs[4][8][64];
    __shared__ float tacc[576];
    int t = threadIdx.x;
    for (int i = t; i < 4096; i += 256) { wq_s[i] = Wq[i]; wk_s[i] = Wk[i]; }
    for (int i = t; i < 2048; i += 256) wv_s[i] = Wv[i];
    if (t < 64) { bq_s[t] = bq[t]; bk_s[t] = bk[t]; }
    if (t >= 64 && t < 96) bv_s[t - 64] = bv[t - 64];
    for (int i = t; i < 576; i += 256) tacc[i] = 0.f;
    __syncthreads();
    int lane = t & 63;
    int w = t >> 6;
    int h = lane >> 4;
    int vcol = lane & 31;
    float hw0 = hopwise[0];
    float tkp = 0.f;
    float tmp_[8];
#pragma unroll
    for (int j = 0; j < 8; j++) tmp_[j] = 0.f;
    int tiles = (NN + 31) >> 5;
    for (int tile = blockIdx.x; tile < tiles; tile += gridDim.x) {
        int n0 = tile * 32 + w * 8;
        __syncthreads();
#pragma unroll
        for (int u = 0; u < 8; u++) {
            int n = n0 + u;
            xs[w][u][lane] = (n < NN) ? x[(size_t)n * 64 + lane] : 0.f;
        }
        __syncthreads();
        float aq[8], ak[8], av[8];
#pragma unroll
        for (int u = 0; u < 8; u++) { aq[u] = 0.f; ak[u] = 0.f; av[u] = 0.f; }
        for (int f = 0; f < 64; f++) {
            float wqv = wq_s[f * 64 + lane];
            float wkv = wk_s[f * 64 + lane];
            float wvv = wv_s[f * 32 + vcol];
#pragma unroll
            for (int u = 0; u < 8; u++) {
                float xf = xs[w][u][f];
                aq[u] = fmaf(xf, wqv, aq[u]);
                ak[u] = fmaf(xf, wkv, ak[u]);
                av[u] = fmaf(xf, wvv, av[u]);
            }
        }
#pragma unroll
        for (int u = 0; u < 8; u++) {
            int n = n0 + u;
            float q = aq[u] + bq_s[lane];
            float k = ak[u] + bk_s[lane];
            float v = av[u] + bv_s[vcol];
            float Qv = q > 0.f ? 1.f + q : expf(q);   // 1 + elu
            float Kv = k > 0.f ? 1.f + k : expf(k);
            float vj[8];
#pragma unroll
            for (int j = 0; j < 8; j++) vj[j] = __shfl(v, h * 8 + j, 64);
            if (n < NN) {
                Qg[(size_t)n * 64 + lane] = Qv;
                float m[8];
#pragma unroll
                for (int j = 0; j < 8; j++) m[j] = Kv * vj[j];
                // teleport sums use UNSCALED values
                tkp += Kv;
#pragma unroll
                for (int j = 0; j < 8; j++) tmp_[j] += m[j];
                // store scaled by dinv[n] (bf16)
                float dv = dinv[n];
                unsigned short* srow = S0 + (size_t)n * SD;
                srow[lane] = f2bf(Kv * dv);
                uint4 pv;
                pv.x = packbf(m[0] * dv, m[1] * dv);
                pv.y = packbf(m[2] * dv, m[3] * dv);
                pv.z = packbf(m[4] * dv, m[5] * dv);
                pv.w = packbf(m[6] * dv, m[7] * dv);
                *(uint4*)(srow + 64 + lane * 8) = pv;
                if (lane < 32) hid[(size_t)n * 32 + lane] = v * hw0;
            }
        }
    }
#pragma unroll
    for (int j = 0; j < 8; j++) atomicAdd(&tacc[lane * 8 + j], tmp_[j]);
    atomicAdd(&tacc[512 + lane], tkp);
    __syncthreads();
    for (int i = t; i < 576; i += 256) atomicAdd(&tMK[i], tacc[i]);
}

// ---------------- propagate one hop + fused attend ----------------
// One wave per destination node. Lane l accumulates K[l] and M[l*8 .. l*8+7].
// Inputs pre-scaled by dinv[src] -> pure adds in the edge loop.

__global__ __launch_bounds__(256) void k_prop(const unsigned short* __restrict__ Sold,
    const int* __restrict__ offs, const int* __restrict__ csr_src,
    const float* __restrict__ dinv, const float* __restrict__ Qg,
    const float* __restrict__ hopwise, const float* __restrict__ headwise,
    int hop, int writeS, unsigned short* __restrict__ Snew, float* __restrict__ hid) {
    int t = threadIdx.x;
    int lane = t & 63;
    int n = (blockIdx.x * 256 + t) >> 6;
    if (n >= NN) return;
    int h = lane >> 4;
    float e0 = expf(headwise[0 * 2 + hop]);
    float e1 = expf(headwise[1 * 2 + hop]);
    float e2 = expf(headwise[2 * 2 + hop]);
    float e3 = expf(headwise[3 * 2 + hop]);
    float esum = e0 + e1 + e2 + e3;
    float eh = (h == 0) ? e0 : ((h == 1) ? e1 : ((h == 2) ? e2 : e3));
    float gam = hopwise[hop + 1] * eh / esum;

    int o0 = offs[n], o1 = offs[n + 1];
    float kacc = 0.f;
    float4 m0 = make_float4(0.f, 0.f, 0.f, 0.f);
    float4 m1 = make_float4(0.f, 0.f, 0.f, 0.f);
    for (int e = o0; e < o1; e++) {
        int src = csr_src[e];
        const unsigned short* srow = Sold + (size_t)src * SD;
        kacc += bf_lo(srow[lane]);
        uint4 mv = *(const uint4*)(srow + 64 + lane * 8);
        m0.x += bf_lo(mv.x); m0.y += bf_hi(mv.x);
        m0.z += bf_lo(mv.y); m0.w += bf_hi(mv.y);
        m1.x += bf_lo(mv.z); m1.y += bf_hi(mv.z);
        m1.z += bf_lo(mv.w); m1.w += bf_hi(mv.w);
    }
    if (writeS) {
        float dv = dinv[n];
        unsigned short* drow = Snew + (size_t)n * SD;
        drow[lane] = f2bf(kacc * dv);
        uint4 pv;
        pv.x = packbf(m0.x * dv, m0.y * dv);
        pv.y = packbf(m0.z * dv, m0.w * dv);
        pv.z = packbf(m1.x * dv, m1.y * dv);
        pv.w = packbf(m1.z * dv, m1.w * dv);
        *(uint4*)(drow + 64 + lane * 8) = pv;
    }
    // attend: Hh[h][j] = sum_i Q[h][i]*M[h][i][j]; Cc[h] = sum_i Q[h][i]*K[h][i]
    float qv = Qg[(size_t)n * 64 + lane];
    float hh[8];
    hh[0] = qv * m0.x; hh[1] = qv * m0.y; hh[2] = qv * m0.z; hh[3] = qv * m0.w;
    hh[4] = qv * m1.x; hh[5] = qv * m1.y; hh[6] = qv * m1.z; hh[7] = qv * m1.w;
    float cc = qv * kacc;
#pragma unroll
    for (int s = 1; s < 16; s <<= 1) {
#pragma unroll
        for (int j = 0; j < 8; j++) hh[j] += __shfl_xor(hh[j], s, 16);
        cc += __shfl_xor(cc, s, 16);
    }
    if ((lane & 15) < 8) {
        int j = lane & 7;
        float val = j < 4 ? (j < 2 ? (j == 0 ? hh[0] : hh[1]) : (j == 2 ? hh[2] : hh[3]))
                          : (j < 6 ? (j == 4 ? hh[4] : hh[5]) : (j == 6 ? hh[6] : hh[7]));
        size_t idx = (size_t)n * 32 + h * 8 + j;
        hid[idx] += gam * val / (cc + CSTF);
    }
}

// ---------------- final: out = hidden @ Wo + bo + teleport * teleportH ----------------

__global__ __launch_bounds__(256) void k_final(const float* __restrict__ hid,
    const float* __restrict__ Qg, const float* __restrict__ Wo,
    const float* __restrict__ bo, const float* __restrict__ tMK,
    const float* __restrict__ teleport, float* __restrict__ out) {
    __shared__ float tm[512];
    __shared__ float tk[64];
    __shared__ float wo[256];
    __shared__ float bos[8];
    int t = threadIdx.x;
    const float invN = 1.0f / (float)NN;
    for (int i = t; i < 512; i += 256) tm[i] = tMK[i] * invN;
    if (t < 64) tk[t] = tMK[512 + t] * invN;
    wo[t] = Wo[t & 255];
    if (t < 8) bos[t] = bo[t];
    __syncthreads();
    float tp = teleport[0];
    int lane = t & 63;
    int sub = lane & 7;
    int g = lane >> 3;
    int wid = (blockIdx.x * 256 + t) >> 6;
    int nwaves = gridDim.x * 4;
    for (int nb = wid * 8; nb < NN; nb += nwaves * 8) {
        int n = nb + g;
        if (n < NN) {
            const float* hrow = hid + (size_t)n * 32;
            const float* qrow = Qg + (size_t)n * 64;
            float o = bos[sub];
#pragma unroll
            for (int m = 0; m < 32; m++) o = fmaf(hrow[m], wo[m * 8 + sub], o);
            float th = 0.f;
#pragma unroll
            for (int h2 = 0; h2 < 4; h2++) {
                float num = 0.f, den = 0.f;
#pragma unroll
                for (int i = 0; i < 16; i++) {
                    float q = qrow[h2 * 16 + i];
                    num = fmaf(q, tm[h2 * 128 + i * 8 + sub], num);
                    den = fmaf(q, tk[h2 * 16 + i], den);
                }
                th += num / (den + CSTF);
            }
            out[(size_t)n * 8 + sub] = o + tp * th;
        }
    }
}

// ---------------- launch ----------------

extern "C" void kernel_launch(void* const* d_in, const int* in_sizes, int n_in,
                              void* d_out, int out_size, void* d_ws, size_t ws_size,
                              hipStream_t stream) {
    const float* nf = (const float*)d_in[0];
    const int* ei = (const int*)d_in[1];
    const float* Wi = (const float*)d_in[2];
    const float* bi = (const float*)d_in[3];
    const float* Wq = (const float*)d_in[4];
    const float* bq = (const float*)d_in[5];
    const float* Wk = (const float*)d_in[6];
    const float* bk = (const float*)d_in[7];
    const float* Wv = (const float*)d_in[8];
    const float* bv = (const float*)d_in[9];
    const float* Wo = (const float*)d_in[10];
    const float* bo = (const float*)d_in[11];
    const float* hopwise = (const float*)d_in[12];
    const float* headwise = (const float*)d_in[13];
    const float* teleport = (const float*)d_in[14];
    float* out = (float*)d_out;

    char* base = (char*)d_ws;
    size_t off = 0;
    auto alloc = [&](size_t bytes) -> void* {
        void* p = base + off;
        off = (off + bytes + 255) & ~(size_t)255;
        return p;
    };
    int* deg = (int*)alloc(NN * 4);
    int* cursor = (int*)alloc(NN * 4);
    int* offs = (int*)alloc((NN + 1) * 4);
    float* dinv = (float*)alloc(NN * 4);
    int* csr_src = (int*)alloc((size_t)NE * 4);
    float* xbuf = (float*)alloc((size_t)NN * 64 * 4);
    float* Qg = (float*)alloc((size_t)NN * 64 * 4);
    float* hid = (float*)alloc((size_t)NN * 32 * 4);
    unsigned short* Sa = (unsigned short*)alloc((size_t)NN * SD * 2);
    unsigned short* Sb = (unsigned short*)alloc((size_t)NN * SD * 2);
    float* tMK = (float*)alloc(576 * 4);

    const int* rowp = ei;
    const int* colp = ei + NE;

    hipMemsetAsync(deg, 0, NN * 4, stream);
    hipMemsetAsync(cursor, 0, NN * 4, stream);
    hipMemsetAsync(tMK, 0, 576 * 4, stream);

    k_deg<<<(NE + 255) / 256, 256, 0, stream>>>(colp, deg);
    k_deginv<<<(NN + 255) / 256, 256, 0, stream>>>(deg, dinv);
    k_scan<<<1, 1024, 0, stream>>>(deg, offs);
    k_scatter<<<(NE + 255) / 256, 256, 0, stream>>>(rowp, colp, offs, cursor, csr_src);
    k_xgemm<<<(NN + 63) / 64, 256, 0, stream>>>(nf, Wi, bi, xbuf);
    k_qkv<<<512, 256, 0, stream>>>(xbuf, Wq, bq, Wk, bk, Wv, bv, hopwise, dinv,
                                   Qg, hid, Sa, tMK);
    k_prop<<<(NN * 64 + 255) / 256, 256, 0, stream>>>(Sa, offs, csr_src, dinv, Qg,
                                                      hopwise, headwise, 0, 1, Sb, hid);
    k_prop<<<(NN * 64 + 255) / 256, 256, 0, stream>>>(Sb, offs, csr_src, dinv, Qg,
                                                      hopwise, headwise, 1, 0, Sb, hid);
    k_final<<<1563, 256, 0, stream>>>(hid, Qg, Wo, bo, tMK, teleport, out);
}

// Round 4
// 631.762 us; speedup vs baseline: 1.8966x; 1.1076x over previous
//
#include <hip/hip_runtime.h>
#include <hip/hip_bf16.h>
#include <stdint.h>
#include <stddef.h>

#define NN 50000
#define NE 800000
#define FIN 500
#define HIDN 64
#define NH 4
#define HCD 16
#define NC 8
// S row: 64 bf16 K (128 B) + 512 fp8 M (512 B) = 640 B
#define SROW 640
#define CSTF 1e-5f

typedef float f32x2 __attribute__((ext_vector_type(2)));

// bf16 helpers (storage-only; math fp32)
__device__ inline float bf_lo(unsigned u) {
    union { unsigned i; float f; } v; v.i = u << 16; return v.f;
}
__device__ inline unsigned short f2bf(float f) {
    union { float f; unsigned i; } v; v.f = f;
    unsigned r = v.i + 0x7fffu + ((v.i >> 16) & 1u);   // RNE
    return (unsigned short)(r >> 16);
}

// ---------------- degree / CSR build ----------------

__global__ void k_deg(const int* __restrict__ col, int* __restrict__ deg) {
    int e = blockIdx.x * blockDim.x + threadIdx.x;
    if (e < NE) atomicAdd(&deg[col[e]], 1);
}

__global__ void k_deginv(const int* __restrict__ deg, float* __restrict__ dinv) {
    int i = blockIdx.x * blockDim.x + threadIdx.x;
    if (i < NN) dinv[i] = deg[i] > 0 ? 1.0f / (float)deg[i] : 0.0f;
}

__global__ __launch_bounds__(1024) void k_scan(const int* __restrict__ deg,
                                               int* __restrict__ offs) {
    __shared__ int sums[1024];
    int t = threadIdx.x;
    const int stripe = (NN + 1023) / 1024;     // 49
    int s0 = t * stripe;
    int s1 = min(s0 + stripe, NN);
    int tot = 0;
    for (int i = s0; i < s1; i++) tot += deg[i];
    sums[t] = tot;
    __syncthreads();
    for (int d = 1; d < 1024; d <<= 1) {
        int add = (t >= d) ? sums[t - d] : 0;
        __syncthreads();
        sums[t] += add;
        __syncthreads();
    }
    int run = (t == 0) ? 0 : sums[t - 1];
    for (int i = s0; i < s1; i++) { offs[i] = run; run += deg[i]; }
    if (t == 1023) offs[NN] = sums[1023];
}

__global__ void k_scatter(const int* __restrict__ row, const int* __restrict__ col,
                          const int* __restrict__ offs, int* __restrict__ cursor,
                          int* __restrict__ csr_src) {
    int e = blockIdx.x * blockDim.x + threadIdx.x;
    if (e < NE) {
        int c = col[e];
        int pos = offs[c] + atomicAdd(&cursor[c], 1);
        csr_src[pos] = row[e];
    }
}

// ---------------- x = relu(nf @ Wi + bi) ----------------

#define XG_TK 32
#define XG_AS 36

__global__ __launch_bounds__(256) void k_xgemm(const float* __restrict__ nf,
                                               const float* __restrict__ Wi,
                                               const float* __restrict__ bi,
                                               float* __restrict__ x) {
    __shared__ __align__(16) float a_s[64 * XG_AS];
    __shared__ __align__(16) float w_s[XG_TK * 64];
    int t = threadIdx.x;
    int cg = t & 15;
    int rg = t >> 4;
    int c0 = cg * 4;
    int n0 = blockIdx.x * 64;

    int a_f4 = t & 7;
    int a_row = t >> 3;
    int w_c4 = (t & 15) * 4;
    int w_k = t >> 4;

    float4 acc[4];
#pragma unroll
    for (int r = 0; r < 4; r++) acc[r] = make_float4(0.f, 0.f, 0.f, 0.f);

    for (int k0 = 0; k0 < FIN; k0 += XG_TK) {
        __syncthreads();
#pragma unroll
        for (int p = 0; p < 2; p++) {
            int row = a_row + p * 32;
            int n = n0 + row;
            int kk = k0 + a_f4 * 4;
            float4 v = make_float4(0.f, 0.f, 0.f, 0.f);
            if (n < NN && kk < FIN)
                v = *(const float4*)&nf[(size_t)n * FIN + kk];
            *(float4*)&a_s[row * XG_AS + a_f4 * 4] = v;
        }
#pragma unroll
        for (int p = 0; p < 2; p++) {
            int kk = w_k + p * 16;
            float4 v = make_float4(0.f, 0.f, 0.f, 0.f);
            if (k0 + kk < FIN)
                v = *(const float4*)&Wi[(size_t)(k0 + kk) * 64 + w_c4];
            *(float4*)&w_s[kk * 64 + w_c4] = v;
        }
        __syncthreads();
#pragma unroll 2
        for (int kk = 0; kk < XG_TK; kk += 4) {
            float4 av[4];
#pragma unroll
            for (int r = 0; r < 4; r++)
                av[r] = *(const float4*)&a_s[(rg * 4 + r) * XG_AS + kk];
#pragma unroll
            for (int j = 0; j < 4; j++) {
                float4 wv = *(const float4*)&w_s[(kk + j) * 64 + c0];
#pragma unroll
                for (int r = 0; r < 4; r++) {
                    float a = (j == 0) ? av[r].x : (j == 1) ? av[r].y
                             : (j == 2) ? av[r].z : av[r].w;
                    acc[r].x = fmaf(a, wv.x, acc[r].x);
                    acc[r].y = fmaf(a, wv.y, acc[r].y);
                    acc[r].z = fmaf(a, wv.z, acc[r].z);
                    acc[r].w = fmaf(a, wv.w, acc[r].w);
                }
            }
        }
    }
    float4 b4 = *(const float4*)&bi[c0];
#pragma unroll
    for (int r = 0; r < 4; r++) {
        int n = n0 + rg * 4 + r;
        if (n < NN) {
            float4 o;
            o.x = fmaxf(acc[r].x + b4.x, 0.f);
            o.y = fmaxf(acc[r].y + b4.y, 0.f);
            o.z = fmaxf(acc[r].z + b4.z, 0.f);
            o.w = fmaxf(acc[r].w + b4.w, 0.f);
            *(float4*)&x[(size_t)n * 64 + c0] = o;
        }
    }
}

// ---------------- QKV + M outer-product + teleport sums ----------------
// S row: K bf16 at [0..127] (value*dinv), M fp8 e4m3 at [128..639]
// (value*dinv*16 -> keeps fp8 in normal range; 1/16 folded into gamma).

__global__ __launch_bounds__(256) void k_qkv(const float* __restrict__ x,
    const float* __restrict__ Wq, const float* __restrict__ bq,
    const float* __restrict__ Wk, const float* __restrict__ bk,
    const float* __restrict__ Wv, const float* __restrict__ bv,
    const float* __restrict__ hopwise, const float* __restrict__ dinv,
    float* __restrict__ Qg, float* __restrict__ hid,
    unsigned char* __restrict__ S0, float* __restrict__ tMK) {
    __shared__ float wq_s[64 * 64], wk_s[64 * 64], wv_s[64 * 32];
    __shared__ float bq_s[64], bk_s[64], bv_s[32];
    __shared__ float xs[4][8][64];
    __shared__ float tacc[576];
    int t = threadIdx.x;
    for (int i = t; i < 4096; i += 256) { wq_s[i] = Wq[i]; wk_s[i] = Wk[i]; }
    for (int i = t; i < 2048; i += 256) wv_s[i] = Wv[i];
    if (t < 64) { bq_s[t] = bq[t]; bk_s[t] = bk[t]; }
    if (t >= 64 && t < 96) bv_s[t - 64] = bv[t - 64];
    for (int i = t; i < 576; i += 256) tacc[i] = 0.f;
    __syncthreads();
    int lane = t & 63;
    int w = t >> 6;
    int h = lane >> 4;
    int vcol = lane & 31;
    float hw0 = hopwise[0];
    float tkp = 0.f;
    float tmp_[8];
#pragma unroll
    for (int j = 0; j < 8; j++) tmp_[j] = 0.f;
    int tiles = (NN + 31) >> 5;
    for (int tile = blockIdx.x; tile < tiles; tile += gridDim.x) {
        int n0 = tile * 32 + w * 8;
        __syncthreads();
#pragma unroll
        for (int u = 0; u < 8; u++) {
            int n = n0 + u;
            xs[w][u][lane] = (n < NN) ? x[(size_t)n * 64 + lane] : 0.f;
        }
        __syncthreads();
        float aq[8], ak[8], av[8];
#pragma unroll
        for (int u = 0; u < 8; u++) { aq[u] = 0.f; ak[u] = 0.f; av[u] = 0.f; }
        for (int f = 0; f < 64; f++) {
            float wqv = wq_s[f * 64 + lane];
            float wkv = wk_s[f * 64 + lane];
            float wvv = wv_s[f * 32 + vcol];
#pragma unroll
            for (int u = 0; u < 8; u++) {
                float xf = xs[w][u][f];
                aq[u] = fmaf(xf, wqv, aq[u]);
                ak[u] = fmaf(xf, wkv, ak[u]);
                av[u] = fmaf(xf, wvv, av[u]);
            }
        }
#pragma unroll
        for (int u = 0; u < 8; u++) {
            int n = n0 + u;
            float q = aq[u] + bq_s[lane];
            float k = ak[u] + bk_s[lane];
            float v = av[u] + bv_s[vcol];
            float Qv = q > 0.f ? 1.f + q : expf(q);   // 1 + elu
            float Kv = k > 0.f ? 1.f + k : expf(k);
            float vj[8];
#pragma unroll
            for (int j = 0; j < 8; j++) vj[j] = __shfl(v, h * 8 + j, 64);
            if (n < NN) {
                Qg[(size_t)n * 64 + lane] = Qv;
                float m[8];
#pragma unroll
                for (int j = 0; j < 8; j++) m[j] = Kv * vj[j];
                // teleport sums use UNSCALED fp32 values
                tkp += Kv;
#pragma unroll
                for (int j = 0; j < 8; j++) tmp_[j] += m[j];
                float dv = dinv[n];
                float s16 = dv * 16.f;
                unsigned char* srow = S0 + (size_t)n * SROW;
                ((unsigned short*)srow)[lane] = f2bf(Kv * dv);
                unsigned u0 = __builtin_amdgcn_cvt_pk_fp8_f32(m[0] * s16, m[1] * s16, 0, false);
                u0 = __builtin_amdgcn_cvt_pk_fp8_f32(m[2] * s16, m[3] * s16, u0, true);
                unsigned u1 = __builtin_amdgcn_cvt_pk_fp8_f32(m[4] * s16, m[5] * s16, 0, false);
                u1 = __builtin_amdgcn_cvt_pk_fp8_f32(m[6] * s16, m[7] * s16, u1, true);
                uint2 pv; pv.x = u0; pv.y = u1;
                *(uint2*)(srow + 128 + lane * 8) = pv;
                if (lane < 32) hid[(size_t)n * 32 + lane] = v * hw0;
            }
        }
    }
#pragma unroll
    for (int j = 0; j < 8; j++) atomicAdd(&tacc[lane * 8 + j], tmp_[j]);
    atomicAdd(&tacc[512 + lane], tkp);
    __syncthreads();
    for (int i = t; i < 576; i += 256) atomicAdd(&tMK[i], tacc[i]);
}

// ---------------- propagate one hop + fused attend ----------------
// One wave per destination node. Lane l accumulates K[l] (bf16) and
// M[l*8..l*8+7] (fp8, pre-scaled by dinv*16 -> pure adds after HW cvt).

__global__ __launch_bounds__(256) void k_prop(const unsigned char* __restrict__ Sold,
    const int* __restrict__ offs, const int* __restrict__ csr_src,
    const float* __restrict__ dinv, const float* __restrict__ Qg,
    const float* __restrict__ hopwise, const float* __restrict__ headwise,
    int hop, int writeS, unsigned char* __restrict__ Snew, float* __restrict__ hid) {
    int t = threadIdx.x;
    int lane = t & 63;
    int n = (blockIdx.x * 256 + t) >> 6;
    if (n >= NN) return;
    int h = lane >> 4;
    float e0 = expf(headwise[0 * 2 + hop]);
    float e1 = expf(headwise[1 * 2 + hop]);
    float e2 = expf(headwise[2 * 2 + hop]);
    float e3 = expf(headwise[3 * 2 + hop]);
    float esum = e0 + e1 + e2 + e3;
    float eh = (h == 0) ? e0 : ((h == 1) ? e1 : ((h == 2) ? e2 : e3));
    // M accumulators carry an extra *16; fold 1/16 into gamma.
    float gam = hopwise[hop + 1] * eh / esum * 0.0625f;

    int o0 = offs[n], o1 = offs[n + 1];
    float kacc = 0.f;
    float4 m0 = make_float4(0.f, 0.f, 0.f, 0.f);
    float4 m1 = make_float4(0.f, 0.f, 0.f, 0.f);
    for (int e = o0; e < o1; e++) {
        int src = csr_src[e];
        const unsigned char* srow = Sold + (size_t)src * SROW;
        kacc += bf_lo(((const unsigned short*)srow)[lane]);
        uint2 mv = *(const uint2*)(srow + 128 + lane * 8);
        f32x2 a0 = __builtin_amdgcn_cvt_pk_f32_fp8(mv.x, false);
        f32x2 a1 = __builtin_amdgcn_cvt_pk_f32_fp8(mv.x, true);
        f32x2 b0 = __builtin_amdgcn_cvt_pk_f32_fp8(mv.y, false);
        f32x2 b1 = __builtin_amdgcn_cvt_pk_f32_fp8(mv.y, true);
        m0.x += a0.x; m0.y += a0.y; m0.z += a1.x; m0.w += a1.y;
        m1.x += b0.x; m1.y += b0.y; m1.z += b1.x; m1.w += b1.y;
    }
    if (writeS) {
        // m regs = 16 * true M1; want stored = trueM1 * dinv * 16 = m * dinv
        float dv = dinv[n];
        unsigned char* drow = Snew + (size_t)n * SROW;
        ((unsigned short*)drow)[lane] = f2bf(kacc * dv);
        unsigned u0 = __builtin_amdgcn_cvt_pk_fp8_f32(m0.x * dv, m0.y * dv, 0, false);
        u0 = __builtin_amdgcn_cvt_pk_fp8_f32(m0.z * dv, m0.w * dv, u0, true);
        unsigned u1 = __builtin_amdgcn_cvt_pk_fp8_f32(m1.x * dv, m1.y * dv, 0, false);
        u1 = __builtin_amdgcn_cvt_pk_fp8_f32(m1.z * dv, m1.w * dv, u1, true);
        uint2 pv; pv.x = u0; pv.y = u1;
        *(uint2*)(drow + 128 + lane * 8) = pv;
    }
    // attend: Hh[h][j] = sum_i Q[h][i]*M[h][i][j]; Cc[h] = sum_i Q[h][i]*K[h][i]
    float qv = Qg[(size_t)n * 64 + lane];
    float hh[8];
    hh[0] = qv * m0.x; hh[1] = qv * m0.y; hh[2] = qv * m0.z; hh[3] = qv * m0.w;
    hh[4] = qv * m1.x; hh[5] = qv * m1.y; hh[6] = qv * m1.z; hh[7] = qv * m1.w;
    float cc = qv * kacc;
#pragma unroll
    for (int s = 1; s < 16; s <<= 1) {
#pragma unroll
        for (int j = 0; j < 8; j++) hh[j] += __shfl_xor(hh[j], s, 16);
        cc += __shfl_xor(cc, s, 16);
    }
    if ((lane & 15) < 8) {
        int j = lane & 7;
        float val = j < 4 ? (j < 2 ? (j == 0 ? hh[0] : hh[1]) : (j == 2 ? hh[2] : hh[3]))
                          : (j < 6 ? (j == 4 ? hh[4] : hh[5]) : (j == 6 ? hh[6] : hh[7]));
        size_t idx = (size_t)n * 32 + h * 8 + j;
        hid[idx] += gam * val / (cc + CSTF);
    }
}

// ---------------- final: out = hidden @ Wo + bo + teleport * teleportH ----------------

__global__ __launch_bounds__(256) void k_final(const float* __restrict__ hid,
    const float* __restrict__ Qg, const float* __restrict__ Wo,
    const float* __restrict__ bo, const float* __restrict__ tMK,
    const float* __restrict__ teleport, float* __restrict__ out) {
    __shared__ float tm[512];
    __shared__ float tk[64];
    __shared__ float wo[256];
    __shared__ float bos[8];
    int t = threadIdx.x;
    const float invN = 1.0f / (float)NN;
    for (int i = t; i < 512; i += 256) tm[i] = tMK[i] * invN;
    if (t < 64) tk[t] = tMK[512 + t] * invN;
    wo[t] = Wo[t & 255];
    if (t < 8) bos[t] = bo[t];
    __syncthreads();
    float tp = teleport[0];
    int lane = t & 63;
    int sub = lane & 7;
    int g = lane >> 3;
    int wid = (blockIdx.x * 256 + t) >> 6;
    int nwaves = gridDim.x * 4;
    for (int nb = wid * 8; nb < NN; nb += nwaves * 8) {
        int n = nb + g;
        if (n < NN) {
            const float* hrow = hid + (size_t)n * 32;
            const float* qrow = Qg + (size_t)n * 64;
            float o = bos[sub];
#pragma unroll
            for (int m = 0; m < 32; m++) o = fmaf(hrow[m], wo[m * 8 + sub], o);
            float th = 0.f;
#pragma unroll
            for (int h2 = 0; h2 < 4; h2++) {
                float num = 0.f, den = 0.f;
#pragma unroll
                for (int i = 0; i < 16; i++) {
                    float q = qrow[h2 * 16 + i];
                    num = fmaf(q, tm[h2 * 128 + i * 8 + sub], num);
                    den = fmaf(q, tk[h2 * 16 + i], den);
                }
                th += num / (den + CSTF);
            }
            out[(size_t)n * 8 + sub] = o + tp * th;
        }
    }
}

// ---------------- launch ----------------

extern "C" void kernel_launch(void* const* d_in, const int* in_sizes, int n_in,
                              void* d_out, int out_size, void* d_ws, size_t ws_size,
                              hipStream_t stream) {
    const float* nf = (const float*)d_in[0];
    const int* ei = (const int*)d_in[1];
    const float* Wi = (const float*)d_in[2];
    const float* bi = (const float*)d_in[3];
    const float* Wq = (const float*)d_in[4];
    const float* bq = (const float*)d_in[5];
    const float* Wk = (const float*)d_in[6];
    const float* bk = (const float*)d_in[7];
    const float* Wv = (const float*)d_in[8];
    const float* bv = (const float*)d_in[9];
    const float* Wo = (const float*)d_in[10];
    const float* bo = (const float*)d_in[11];
    const float* hopwise = (const float*)d_in[12];
    const float* headwise = (const float*)d_in[13];
    const float* teleport = (const float*)d_in[14];
    float* out = (float*)d_out;

    char* base = (char*)d_ws;
    size_t off = 0;
    auto alloc = [&](size_t bytes) -> void* {
        void* p = base + off;
        off = (off + bytes + 255) & ~(size_t)255;
        return p;
    };
    int* deg = (int*)alloc(NN * 4);
    int* cursor = (int*)alloc(NN * 4);
    int* offs = (int*)alloc((NN + 1) * 4);
    float* dinv = (float*)alloc(NN * 4);
    int* csr_src = (int*)alloc((size_t)NE * 4);
    float* xbuf = (float*)alloc((size_t)NN * 64 * 4);
    float* Qg = (float*)alloc((size_t)NN * 64 * 4);
    float* hid = (float*)alloc((size_t)NN * 32 * 4);
    unsigned char* Sa = (unsigned char*)alloc((size_t)NN * SROW);
    unsigned char* Sb = (unsigned char*)alloc((size_t)NN * SROW);
    float* tMK = (float*)alloc(576 * 4);

    const int* rowp = ei;
    const int* colp = ei + NE;

    hipMemsetAsync(deg, 0, NN * 4, stream);
    hipMemsetAsync(cursor, 0, NN * 4, stream);
    hipMemsetAsync(tMK, 0, 576 * 4, stream);

    k_deg<<<(NE + 255) / 256, 256, 0, stream>>>(colp, deg);
    k_deginv<<<(NN + 255) / 256, 256, 0, stream>>>(deg, dinv);
    k_scan<<<1, 1024, 0, stream>>>(deg, offs);
    k_scatter<<<(NE + 255) / 256, 256, 0, stream>>>(rowp, colp, offs, cursor, csr_src);
    k_xgemm<<<(NN + 63) / 64, 256, 0, stream>>>(nf, Wi, bi, xbuf);
    k_qkv<<<512, 256, 0, stream>>>(xbuf, Wq, bq, Wk, bk, Wv, bv, hopwise, dinv,
                                   Qg, hid, Sa, tMK);
    k_prop<<<(NN * 64 + 255) / 256, 256, 0, stream>>>(Sa, offs, csr_src, dinv, Qg,
                                                      hopwise, headwise, 0, 1, Sb, hid);
    k_prop<<<(NN * 64 + 255) / 256, 256, 0, stream>>>(Sb, offs, csr_src, dinv, Qg,
                                                      hopwise, headwise, 1, 0, Sb, hid);
    k_final<<<1563, 256, 0, stream>>>(hid, Qg, Wo, bo, tMK, teleport, out);
}

// Round 5
// 498.979 us; speedup vs baseline: 2.4013x; 1.2661x over previous
//
#include <hip/hip_runtime.h>
#include <hip/hip_bf16.h>
#include <stdint.h>
#include <stddef.h>

#define NN 50000
#define NE 800000
#define FIN 500
#define HIDN 64
#define NH 4
#define HCD 16
#define NC 8
// kv row: 64 bf16 Kf*dinv (128 B) + 32 bf16 V (64 B) = 192 B
#define KVROW 192
// S1 row: 64 bf16 K1 (128 B) + 512 fp8 M1 (512 B) = 640 B
#define SROW 640
#define CSTF 1e-5f
#define SCAN_NB 196   // ceil(50000/256)

typedef float f32x2 __attribute__((ext_vector_type(2)));

// bf16 helpers (storage-only; math fp32)
__device__ inline float bf_lo(unsigned u) {
    union { unsigned i; float f; } v; v.i = u << 16; return v.f;
}
__device__ inline float bf_hi(unsigned u) {
    union { unsigned i; float f; } v; v.i = u & 0xffff0000u; return v.f;
}
__device__ inline unsigned short f2bf(float f) {
    union { float f; unsigned i; } v; v.f = f;
    unsigned r = v.i + 0x7fffu + ((v.i >> 16) & 1u);   // RNE
    return (unsigned short)(r >> 16);
}

// ---------------- degree / CSR build ----------------

__global__ void k_deg(const int* __restrict__ col, int* __restrict__ deg) {
    int e = blockIdx.x * blockDim.x + threadIdx.x;
    if (e < NE) atomicAdd(&deg[col[e]], 1);
}

__global__ void k_deginv(const int* __restrict__ deg, float* __restrict__ dinv,
                         int* __restrict__ cursor) {
    int i = blockIdx.x * blockDim.x + threadIdx.x;
    if (i < NN) {
        dinv[i] = deg[i] > 0 ? 1.0f / (float)deg[i] : 0.0f;
        cursor[i] = 0;
    }
}

// 3-phase multi-block exclusive scan of deg -> offs
__global__ void k_bsum(const int* __restrict__ deg, int* __restrict__ bsum) {
    __shared__ int red[256];
    int b = blockIdx.x, t = threadIdx.x;
    int i = b * 256 + t;
    red[t] = (i < NN) ? deg[i] : 0;
    __syncthreads();
    for (int d = 128; d > 0; d >>= 1) {
        if (t < d) red[t] += red[t + d];
        __syncthreads();
    }
    if (t == 0) bsum[b] = red[0];
}

__global__ void k_bscan(const int* __restrict__ bsum, int* __restrict__ bex) {
    __shared__ int s[256];
    int t = threadIdx.x;
    int own = (t < SCAN_NB) ? bsum[t] : 0;
    s[t] = own;
    __syncthreads();
    for (int d = 1; d < 256; d <<= 1) {
        int v = (t >= d) ? s[t - d] : 0;
        __syncthreads();
        s[t] += v;
        __syncthreads();
    }
    if (t < SCAN_NB) bex[t] = s[t] - own;   // exclusive
}

__global__ void k_expand(const int* __restrict__ deg, const int* __restrict__ bex,
                         int* __restrict__ offs) {
    __shared__ int s[256];
    int b = blockIdx.x, t = threadIdx.x;
    int i = b * 256 + t;
    int v = (i < NN) ? deg[i] : 0;
    s[t] = v;
    __syncthreads();
    for (int d = 1; d < 256; d <<= 1) {
        int a = (t >= d) ? s[t - d] : 0;
        __syncthreads();
        s[t] += a;
        __syncthreads();
    }
    int excl = s[t] - v + bex[b];
    if (i < NN) offs[i] = excl;
    if (i == NN - 1) offs[NN] = excl + v;
}

__global__ void k_scatter(const int* __restrict__ row, const int* __restrict__ col,
                          const int* __restrict__ offs, int* __restrict__ cursor,
                          int* __restrict__ csr_src) {
    int e = blockIdx.x * blockDim.x + threadIdx.x;
    if (e < NE) {
        int c = col[e];
        int pos = offs[c] + atomicAdd(&cursor[c], 1);
        csr_src[pos] = row[e];
    }
}

// ---------------- x = relu(nf @ Wi + bi) ----------------

#define XG_TK 32
#define XG_AS 36

__global__ __launch_bounds__(256) void k_xgemm(const float* __restrict__ nf,
                                               const float* __restrict__ Wi,
                                               const float* __restrict__ bi,
                                               float* __restrict__ x) {
    __shared__ __align__(16) float a_s[64 * XG_AS];
    __shared__ __align__(16) float w_s[XG_TK * 64];
    int t = threadIdx.x;
    int cg = t & 15;
    int rg = t >> 4;
    int c0 = cg * 4;
    int n0 = blockIdx.x * 64;

    int a_f4 = t & 7;
    int a_row = t >> 3;
    int w_c4 = (t & 15) * 4;
    int w_k = t >> 4;

    float4 acc[4];
#pragma unroll
    for (int r = 0; r < 4; r++) acc[r] = make_float4(0.f, 0.f, 0.f, 0.f);

    for (int k0 = 0; k0 < FIN; k0 += XG_TK) {
        __syncthreads();
#pragma unroll
        for (int p = 0; p < 2; p++) {
            int row = a_row + p * 32;
            int n = n0 + row;
            int kk = k0 + a_f4 * 4;
            float4 v = make_float4(0.f, 0.f, 0.f, 0.f);
            if (n < NN && kk < FIN)
                v = *(const float4*)&nf[(size_t)n * FIN + kk];
            *(float4*)&a_s[row * XG_AS + a_f4 * 4] = v;
        }
#pragma unroll
        for (int p = 0; p < 2; p++) {
            int kk = w_k + p * 16;
            float4 v = make_float4(0.f, 0.f, 0.f, 0.f);
            if (k0 + kk < FIN)
                v = *(const float4*)&Wi[(size_t)(k0 + kk) * 64 + w_c4];
            *(float4*)&w_s[kk * 64 + w_c4] = v;
        }
        __syncthreads();
#pragma unroll 2
        for (int kk = 0; kk < XG_TK; kk += 4) {
            float4 av[4];
#pragma unroll
            for (int r = 0; r < 4; r++)
                av[r] = *(const float4*)&a_s[(rg * 4 + r) * XG_AS + kk];
#pragma unroll
            for (int j = 0; j < 4; j++) {
                float4 wv = *(const float4*)&w_s[(kk + j) * 64 + c0];
#pragma unroll
                for (int r = 0; r < 4; r++) {
                    float a = (j == 0) ? av[r].x : (j == 1) ? av[r].y
                             : (j == 2) ? av[r].z : av[r].w;
                    acc[r].x = fmaf(a, wv.x, acc[r].x);
                    acc[r].y = fmaf(a, wv.y, acc[r].y);
                    acc[r].z = fmaf(a, wv.z, acc[r].z);
                    acc[r].w = fmaf(a, wv.w, acc[r].w);
                }
            }
        }
    }
    float4 b4 = *(const float4*)&bi[c0];
#pragma unroll
    for (int r = 0; r < 4; r++) {
        int n = n0 + rg * 4 + r;
        if (n < NN) {
            float4 o;
            o.x = fmaxf(acc[r].x + b4.x, 0.f);
            o.y = fmaxf(acc[r].y + b4.y, 0.f);
            o.z = fmaxf(acc[r].z + b4.z, 0.f);
            o.w = fmaxf(acc[r].w + b4.w, 0.f);
            *(float4*)&x[(size_t)n * 64 + c0] = o;
        }
    }
}

// ---------------- QKV + kv row + teleport sums ----------------
// kv row: [0..127] Kf*dinv bf16, [128..191] V bf16 (unscaled).
// M0*dinv = (Kf*dinv) (x) V is formed on the fly in k_hop0.

__global__ __launch_bounds__(256) void k_qkv(const float* __restrict__ x,
    const float* __restrict__ Wq, const float* __restrict__ bq,
    const float* __restrict__ Wk, const float* __restrict__ bk,
    const float* __restrict__ Wv, const float* __restrict__ bv,
    const float* __restrict__ hopwise, const float* __restrict__ dinv,
    float* __restrict__ Qg, float* __restrict__ hid,
    unsigned char* __restrict__ kv0, float* __restrict__ tMK) {
    __shared__ float wq_s[64 * 64], wk_s[64 * 64], wv_s[64 * 32];
    __shared__ float bq_s[64], bk_s[64], bv_s[32];
    __shared__ float xs[4][8][64];
    __shared__ float tacc[576];
    int t = threadIdx.x;
    for (int i = t; i < 4096; i += 256) { wq_s[i] = Wq[i]; wk_s[i] = Wk[i]; }
    for (int i = t; i < 2048; i += 256) wv_s[i] = Wv[i];
    if (t < 64) { bq_s[t] = bq[t]; bk_s[t] = bk[t]; }
    if (t >= 64 && t < 96) bv_s[t - 64] = bv[t - 64];
    for (int i = t; i < 576; i += 256) tacc[i] = 0.f;
    __syncthreads();
    int lane = t & 63;
    int w = t >> 6;
    int h = lane >> 4;
    int vcol = lane & 31;
    float hw0 = hopwise[0];
    float tkp = 0.f;
    float tmp_[8];
#pragma unroll
    for (int j = 0; j < 8; j++) tmp_[j] = 0.f;
    int tiles = (NN + 31) >> 5;
    for (int tile = blockIdx.x; tile < tiles; tile += gridDim.x) {
        int n0 = tile * 32 + w * 8;
        __syncthreads();
#pragma unroll
        for (int u = 0; u < 8; u++) {
            int n = n0 + u;
            xs[w][u][lane] = (n < NN) ? x[(size_t)n * 64 + lane] : 0.f;
        }
        __syncthreads();
        float aq[8], ak[8], av[8];
#pragma unroll
        for (int u = 0; u < 8; u++) { aq[u] = 0.f; ak[u] = 0.f; av[u] = 0.f; }
        for (int f = 0; f < 64; f++) {
            float wqv = wq_s[f * 64 + lane];
            float wkv = wk_s[f * 64 + lane];
            float wvv = wv_s[f * 32 + vcol];
#pragma unroll
            for (int u = 0; u < 8; u++) {
                float xf = xs[w][u][f];
                aq[u] = fmaf(xf, wqv, aq[u]);
                ak[u] = fmaf(xf, wkv, ak[u]);
                av[u] = fmaf(xf, wvv, av[u]);
            }
        }
#pragma unroll
        for (int u = 0; u < 8; u++) {
            int n = n0 + u;
            float q = aq[u] + bq_s[lane];
            float k = ak[u] + bk_s[lane];
            float v = av[u] + bv_s[vcol];
            float Qv = q > 0.f ? 1.f + q : expf(q);   // 1 + elu
            float Kv = k > 0.f ? 1.f + k : expf(k);
            if (n < NN) {
                Qg[(size_t)n * 64 + lane] = Qv;
                // teleport sums (UNSCALED): tacc M needs Kv * V[h*8+j]
                float vj[8];
#pragma unroll
                for (int j = 0; j < 8; j++) vj[j] = __shfl(v, h * 8 + j, 64);
                tkp += Kv;
#pragma unroll
                for (int j = 0; j < 8; j++) tmp_[j] += Kv * vj[j];
                float dv = dinv[n];
                unsigned short* kvrow = (unsigned short*)(kv0 + (size_t)n * KVROW);
                kvrow[lane] = f2bf(Kv * dv);
                if (lane < 32) kvrow[64 + lane] = f2bf(v);
                if (lane < 32) hid[(size_t)n * 32 + lane] = v * hw0;
            }
        }
    }
#pragma unroll
    for (int j = 0; j < 8; j++) atomicAdd(&tacc[lane * 8 + j], tmp_[j]);
    atomicAdd(&tacc[512 + lane], tkp);
    __syncthreads();
    for (int i = t; i < 576; i += 256) atomicAdd(&tMK[i], tacc[i]);
}

// ---------------- hop 0: gather Kf/V, outer-product on the fly ----------------
// One wave per destination node. Lane l = (h=l>>4, i=l&15): accumulates
// K1[l] and M1[h,i,0..7]. V broadcast: 16-B load shared by all lanes of a head.

__global__ __launch_bounds__(256) void k_hop0(const unsigned char* __restrict__ kv0,
    const int* __restrict__ offs, const int* __restrict__ csr_src,
    const float* __restrict__ dinv, const float* __restrict__ Qg,
    const float* __restrict__ hopwise, const float* __restrict__ headwise,
    unsigned char* __restrict__ S1, float* __restrict__ hid) {
    int t = threadIdx.x;
    int lane = t & 63;
    int n = (blockIdx.x * 256 + t) >> 6;
    if (n >= NN) return;
    int h = lane >> 4;
    float e0 = expf(headwise[0 * 2 + 0]);
    float e1 = expf(headwise[1 * 2 + 0]);
    float e2 = expf(headwise[2 * 2 + 0]);
    float e3 = expf(headwise[3 * 2 + 0]);
    float esum = e0 + e1 + e2 + e3;
    float eh = (h == 0) ? e0 : ((h == 1) ? e1 : ((h == 2) ? e2 : e3));
    float gam = hopwise[1] * eh / esum;

    int hoff = 128 + h * 16;
    int o0 = offs[n], o1 = offs[n + 1];
    float kacc = 0.f;
    float4 m0 = make_float4(0.f, 0.f, 0.f, 0.f);
    float4 m1 = make_float4(0.f, 0.f, 0.f, 0.f);
    int e = o0;
    for (; e + 1 < o1; e += 2) {
        int sa = csr_src[e];
        int sb = csr_src[e + 1];
        const unsigned char* ra = kv0 + (size_t)sa * KVROW;
        const unsigned char* rb = kv0 + (size_t)sb * KVROW;
        float ka = bf_lo(((const unsigned short*)ra)[lane]);
        uint4 va = *(const uint4*)(ra + hoff);
        float kb = bf_lo(((const unsigned short*)rb)[lane]);
        uint4 vb = *(const uint4*)(rb + hoff);
        kacc += ka;
        m0.x = fmaf(ka, bf_lo(va.x), m0.x); m0.y = fmaf(ka, bf_hi(va.x), m0.y);
        m0.z = fmaf(ka, bf_lo(va.y), m0.z); m0.w = fmaf(ka, bf_hi(va.y), m0.w);
        m1.x = fmaf(ka, bf_lo(va.z), m1.x); m1.y = fmaf(ka, bf_hi(va.z), m1.y);
        m1.z = fmaf(ka, bf_lo(va.w), m1.z); m1.w = fmaf(ka, bf_hi(va.w), m1.w);
        kacc += kb;
        m0.x = fmaf(kb, bf_lo(vb.x), m0.x); m0.y = fmaf(kb, bf_hi(vb.x), m0.y);
        m0.z = fmaf(kb, bf_lo(vb.y), m0.z); m0.w = fmaf(kb, bf_hi(vb.y), m0.w);
        m1.x = fmaf(kb, bf_lo(vb.z), m1.x); m1.y = fmaf(kb, bf_hi(vb.z), m1.y);
        m1.z = fmaf(kb, bf_lo(vb.w), m1.z); m1.w = fmaf(kb, bf_hi(vb.w), m1.w);
    }
    if (e < o1) {
        int sa = csr_src[e];
        const unsigned char* ra = kv0 + (size_t)sa * KVROW;
        float ka = bf_lo(((const unsigned short*)ra)[lane]);
        uint4 va = *(const uint4*)(ra + hoff);
        kacc += ka;
        m0.x = fmaf(ka, bf_lo(va.x), m0.x); m0.y = fmaf(ka, bf_hi(va.x), m0.y);
        m0.z = fmaf(ka, bf_lo(va.y), m0.z); m0.w = fmaf(ka, bf_hi(va.y), m0.w);
        m1.x = fmaf(ka, bf_lo(va.z), m1.x); m1.y = fmaf(ka, bf_hi(va.z), m1.y);
        m1.z = fmaf(ka, bf_lo(va.w), m1.z); m1.w = fmaf(ka, bf_hi(va.w), m1.w);
    }
    // write S1: K1 bf16 (*dinv), M1 fp8 (*dinv*16; 1/16 folded into hop-1 gamma)
    {
        float dv = dinv[n];
        float s16 = dv * 16.f;
        unsigned char* drow = S1 + (size_t)n * SROW;
        ((unsigned short*)drow)[lane] = f2bf(kacc * dv);
        unsigned u0 = __builtin_amdgcn_cvt_pk_fp8_f32(m0.x * s16, m0.y * s16, 0, false);
        u0 = __builtin_amdgcn_cvt_pk_fp8_f32(m0.z * s16, m0.w * s16, u0, true);
        unsigned u1 = __builtin_amdgcn_cvt_pk_fp8_f32(m1.x * s16, m1.y * s16, 0, false);
        u1 = __builtin_amdgcn_cvt_pk_fp8_f32(m1.z * s16, m1.w * s16, u1, true);
        uint2 pv; pv.x = u0; pv.y = u1;
        *(uint2*)(drow + 128 + lane * 8) = pv;
    }
    // attend (true-scale m, kacc)
    float qv = Qg[(size_t)n * 64 + lane];
    float hh[8];
    hh[0] = qv * m0.x; hh[1] = qv * m0.y; hh[2] = qv * m0.z; hh[3] = qv * m0.w;
    hh[4] = qv * m1.x; hh[5] = qv * m1.y; hh[6] = qv * m1.z; hh[7] = qv * m1.w;
    float cc = qv * kacc;
#pragma unroll
    for (int s = 1; s < 16; s <<= 1) {
#pragma unroll
        for (int j = 0; j < 8; j++) hh[j] += __shfl_xor(hh[j], s, 16);
        cc += __shfl_xor(cc, s, 16);
    }
    if ((lane & 15) < 8) {
        int j = lane & 7;
        float val = j < 4 ? (j < 2 ? (j == 0 ? hh[0] : hh[1]) : (j == 2 ? hh[2] : hh[3]))
                          : (j < 6 ? (j == 4 ? hh[4] : hh[5]) : (j == 6 ? hh[6] : hh[7]));
        size_t idx = (size_t)n * 32 + h * 8 + j;
        hid[idx] += gam * val / (cc + CSTF);
    }
}

// ---------------- hop 1: gather S1 (bf16 K + fp8 M), attend ----------------

__global__ __launch_bounds__(256) void k_prop1(const unsigned char* __restrict__ Sold,
    const int* __restrict__ offs, const int* __restrict__ csr_src,
    const float* __restrict__ Qg, const float* __restrict__ hopwise,
    const float* __restrict__ headwise, float* __restrict__ hid) {
    int t = threadIdx.x;
    int lane = t & 63;
    int n = (blockIdx.x * 256 + t) >> 6;
    if (n >= NN) return;
    int h = lane >> 4;
    float e0 = expf(headwise[0 * 2 + 1]);
    float e1 = expf(headwise[1 * 2 + 1]);
    float e2 = expf(headwise[2 * 2 + 1]);
    float e3 = expf(headwise[3 * 2 + 1]);
    float esum = e0 + e1 + e2 + e3;
    float eh = (h == 0) ? e0 : ((h == 1) ? e1 : ((h == 2) ? e2 : e3));
    // M carries an extra *16; fold 1/16 into gamma.
    float gam = hopwise[2] * eh / esum * 0.0625f;

    int o0 = offs[n], o1 = offs[n + 1];
    float kacc = 0.f;
    float4 m0 = make_float4(0.f, 0.f, 0.f, 0.f);
    float4 m1 = make_float4(0.f, 0.f, 0.f, 0.f);
    int e = o0;
    for (; e + 1 < o1; e += 2) {
        int sa = csr_src[e];
        int sb = csr_src[e + 1];
        const unsigned char* ra = Sold + (size_t)sa * SROW;
        const unsigned char* rb = Sold + (size_t)sb * SROW;
        float ka = bf_lo(((const unsigned short*)ra)[lane]);
        uint2 mva = *(const uint2*)(ra + 128 + lane * 8);
        float kb = bf_lo(((const unsigned short*)rb)[lane]);
        uint2 mvb = *(const uint2*)(rb + 128 + lane * 8);
        kacc += ka;
        {
            f32x2 a0 = __builtin_amdgcn_cvt_pk_f32_fp8(mva.x, false);
            f32x2 a1 = __builtin_amdgcn_cvt_pk_f32_fp8(mva.x, true);
            f32x2 b0 = __builtin_amdgcn_cvt_pk_f32_fp8(mva.y, false);
            f32x2 b1 = __builtin_amdgcn_cvt_pk_f32_fp8(mva.y, true);
            m0.x += a0.x; m0.y += a0.y; m0.z += a1.x; m0.w += a1.y;
            m1.x += b0.x; m1.y += b0.y; m1.z += b1.x; m1.w += b1.y;
        }
        kacc += kb;
        {
            f32x2 a0 = __builtin_amdgcn_cvt_pk_f32_fp8(mvb.x, false);
            f32x2 a1 = __builtin_amdgcn_cvt_pk_f32_fp8(mvb.x, true);
            f32x2 b0 = __builtin_amdgcn_cvt_pk_f32_fp8(mvb.y, false);
            f32x2 b1 = __builtin_amdgcn_cvt_pk_f32_fp8(mvb.y, true);
            m0.x += a0.x; m0.y += a0.y; m0.z += a1.x; m0.w += a1.y;
            m1.x += b0.x; m1.y += b0.y; m1.z += b1.x; m1.w += b1.y;
        }
    }
    if (e < o1) {
        int sa = csr_src[e];
        const unsigned char* ra = Sold + (size_t)sa * SROW;
        float ka = bf_lo(((const unsigned short*)ra)[lane]);
        uint2 mva = *(const uint2*)(ra + 128 + lane * 8);
        kacc += ka;
        f32x2 a0 = __builtin_amdgcn_cvt_pk_f32_fp8(mva.x, false);
        f32x2 a1 = __builtin_amdgcn_cvt_pk_f32_fp8(mva.x, true);
        f32x2 b0 = __builtin_amdgcn_cvt_pk_f32_fp8(mva.y, false);
        f32x2 b1 = __builtin_amdgcn_cvt_pk_f32_fp8(mva.y, true);
        m0.x += a0.x; m0.y += a0.y; m0.z += a1.x; m0.w += a1.y;
        m1.x += b0.x; m1.y += b0.y; m1.z += b1.x; m1.w += b1.y;
    }
    float qv = Qg[(size_t)n * 64 + lane];
    float hh[8];
    hh[0] = qv * m0.x; hh[1] = qv * m0.y; hh[2] = qv * m0.z; hh[3] = qv * m0.w;
    hh[4] = qv * m1.x; hh[5] = qv * m1.y; hh[6] = qv * m1.z; hh[7] = qv * m1.w;
    float cc = qv * kacc;
#pragma unroll
    for (int s = 1; s < 16; s <<= 1) {
#pragma unroll
        for (int j = 0; j < 8; j++) hh[j] += __shfl_xor(hh[j], s, 16);
        cc += __shfl_xor(cc, s, 16);
    }
    if ((lane & 15) < 8) {
        int j = lane & 7;
        float val = j < 4 ? (j < 2 ? (j == 0 ? hh[0] : hh[1]) : (j == 2 ? hh[2] : hh[3]))
                          : (j < 6 ? (j == 4 ? hh[4] : hh[5]) : (j == 6 ? hh[6] : hh[7]));
        size_t idx = (size_t)n * 32 + h * 8 + j;
        hid[idx] += gam * val / (cc + CSTF);
    }
}

// ---------------- final: out = hidden @ Wo + bo + teleport * teleportH ----------------

__global__ __launch_bounds__(256) void k_final(const float* __restrict__ hid,
    const float* __restrict__ Qg, const float* __restrict__ Wo,
    const float* __restrict__ bo, const float* __restrict__ tMK,
    const float* __restrict__ teleport, float* __restrict__ out) {
    __shared__ float tm[512];
    __shared__ float tk[64];
    __shared__ float wo[256];
    __shared__ float bos[8];
    int t = threadIdx.x;
    const float invN = 1.0f / (float)NN;
    for (int i = t; i < 512; i += 256) tm[i] = tMK[i] * invN;
    if (t < 64) tk[t] = tMK[512 + t] * invN;
    wo[t] = Wo[t & 255];
    if (t < 8) bos[t] = bo[t];
    __syncthreads();
    float tp = teleport[0];
    int lane = t & 63;
    int sub = lane & 7;
    int g = lane >> 3;
    int wid = (blockIdx.x * 256 + t) >> 6;
    int nwaves = gridDim.x * 4;
    for (int nb = wid * 8; nb < NN; nb += nwaves * 8) {
        int n = nb + g;
        if (n < NN) {
            const float* hrow = hid + (size_t)n * 32;
            const float* qrow = Qg + (size_t)n * 64;
            float o = bos[sub];
#pragma unroll
            for (int m = 0; m < 32; m++) o = fmaf(hrow[m], wo[m * 8 + sub], o);
            float th = 0.f;
#pragma unroll
            for (int h2 = 0; h2 < 4; h2++) {
                float num = 0.f, den = 0.f;
#pragma unroll
                for (int i = 0; i < 16; i++) {
                    float q = qrow[h2 * 16 + i];
                    num = fmaf(q, tm[h2 * 128 + i * 8 + sub], num);
                    den = fmaf(q, tk[h2 * 16 + i], den);
                }
                th += num / (den + CSTF);
            }
            out[(size_t)n * 8 + sub] = o + tp * th;
        }
    }
}

// ---------------- launch ----------------

extern "C" void kernel_launch(void* const* d_in, const int* in_sizes, int n_in,
                              void* d_out, int out_size, void* d_ws, size_t ws_size,
                              hipStream_t stream) {
    const float* nf = (const float*)d_in[0];
    const int* ei = (const int*)d_in[1];
    const float* Wi = (const float*)d_in[2];
    const float* bi = (const float*)d_in[3];
    const float* Wq = (const float*)d_in[4];
    const float* bq = (const float*)d_in[5];
    const float* Wk = (const float*)d_in[6];
    const float* bk = (const float*)d_in[7];
    const float* Wv = (const float*)d_in[8];
    const float* bv = (const float*)d_in[9];
    const float* Wo = (const float*)d_in[10];
    const float* bo = (const float*)d_in[11];
    const float* hopwise = (const float*)d_in[12];
    const float* headwise = (const float*)d_in[13];
    const float* teleport = (const float*)d_in[14];
    float* out = (float*)d_out;

    char* base = (char*)d_ws;
    size_t off = 0;
    auto alloc = [&](size_t bytes) -> void* {
        void* p = base + off;
        off = (off + bytes + 255) & ~(size_t)255;
        return p;
    };
    int* deg = (int*)alloc(NN * 4);
    int* cursor = (int*)alloc(NN * 4);
    int* offs = (int*)alloc((NN + 1) * 4);
    int* bsum = (int*)alloc(256 * 4);
    int* bex = (int*)alloc(256 * 4);
    float* dinv = (float*)alloc(NN * 4);
    int* csr_src = (int*)alloc((size_t)NE * 4);
    float* xbuf = (float*)alloc((size_t)NN * 64 * 4);
    float* Qg = (float*)alloc((size_t)NN * 64 * 4);
    float* hid = (float*)alloc((size_t)NN * 32 * 4);
    unsigned char* kv0 = (unsigned char*)alloc((size_t)NN * KVROW);
    unsigned char* S1 = (unsigned char*)alloc((size_t)NN * SROW);
    float* tMK = (float*)alloc(576 * 4);

    const int* rowp = ei;
    const int* colp = ei + NE;

    hipMemsetAsync(deg, 0, NN * 4, stream);
    hipMemsetAsync(tMK, 0, 576 * 4, stream);

    k_deg<<<(NE + 255) / 256, 256, 0, stream>>>(colp, deg);
    k_deginv<<<(NN + 255) / 256, 256, 0, stream>>>(deg, dinv, cursor);
    k_bsum<<<SCAN_NB, 256, 0, stream>>>(deg, bsum);
    k_bscan<<<1, 256, 0, stream>>>(bsum, bex);
    k_expand<<<SCAN_NB, 256, 0, stream>>>(deg, bex, offs);
    k_scatter<<<(NE + 255) / 256, 256, 0, stream>>>(rowp, colp, offs, cursor, csr_src);
    k_xgemm<<<(NN + 63) / 64, 256, 0, stream>>>(nf, Wi, bi, xbuf);
    k_qkv<<<512, 256, 0, stream>>>(xbuf, Wq, bq, Wk, bk, Wv, bv, hopwise, dinv,
                                   Qg, hid, kv0, tMK);
    k_hop0<<<(NN * 64 + 255) / 256, 256, 0, stream>>>(kv0, offs, csr_src, dinv, Qg,
                                                      hopwise, headwise, S1, hid);
    k_prop1<<<(NN * 64 + 255) / 256, 256, 0, stream>>>(S1, offs, csr_src, Qg,
                                                       hopwise, headwise, hid);
    k_final<<<1563, 256, 0, stream>>>(hid, Qg, Wo, bo, tMK, teleport, out);
}

// Round 6
// 491.293 us; speedup vs baseline: 2.4389x; 1.0156x over previous
//
#include <hip/hip_runtime.h>
#include <hip/hip_bf16.h>
#include <stdint.h>
#include <stddef.h>

#define NN 50000
#define NE 800000
#define FIN 500
#define HIDN 64
#define NH 4
#define HCD 16
#define NC 8
// kv row: 64 bf16 Kf*dinv (128 B) + 32 bf16 V (64 B) = 192 B
#define KVROW 192
// S1 row: 64 bf16 K1 (128 B) + 512 fp8 M1 (512 B) = 640 B
#define SROW 640
#define CSTF 1e-5f
#define SCAN_NB 196   // ceil(50000/256)

typedef float f32x2 __attribute__((ext_vector_type(2)));
typedef __attribute__((ext_vector_type(8))) short bf16x8;
typedef __attribute__((ext_vector_type(4))) float f32x4;

// bf16 helpers (storage-only; math fp32)
__device__ inline float bf_lo(unsigned u) {
    union { unsigned i; float f; } v; v.i = u << 16; return v.f;
}
__device__ inline float bf_hi(unsigned u) {
    union { unsigned i; float f; } v; v.i = u & 0xffff0000u; return v.f;
}
__device__ inline unsigned short f2bf(float f) {
    union { float f; unsigned i; } v; v.f = f;
    unsigned r = v.i + 0x7fffu + ((v.i >> 16) & 1u);   // RNE
    return (unsigned short)(r >> 16);
}

// ---------------- degree / CSR build ----------------

__global__ void k_deg(const int* __restrict__ col, int* __restrict__ deg) {
    int e = blockIdx.x * blockDim.x + threadIdx.x;
    if (e < NE) atomicAdd(&deg[col[e]], 1);
}

__global__ void k_deginv(const int* __restrict__ deg, float* __restrict__ dinv,
                         int* __restrict__ cursor) {
    int i = blockIdx.x * blockDim.x + threadIdx.x;
    if (i < NN) {
        dinv[i] = deg[i] > 0 ? 1.0f / (float)deg[i] : 0.0f;
        cursor[i] = 0;
    }
}

// 3-phase multi-block exclusive scan of deg -> offs
__global__ void k_bsum(const int* __restrict__ deg, int* __restrict__ bsum) {
    __shared__ int red[256];
    int b = blockIdx.x, t = threadIdx.x;
    int i = b * 256 + t;
    red[t] = (i < NN) ? deg[i] : 0;
    __syncthreads();
    for (int d = 128; d > 0; d >>= 1) {
        if (t < d) red[t] += red[t + d];
        __syncthreads();
    }
    if (t == 0) bsum[b] = red[0];
}

__global__ void k_bscan(const int* __restrict__ bsum, int* __restrict__ bex) {
    __shared__ int s[256];
    int t = threadIdx.x;
    int own = (t < SCAN_NB) ? bsum[t] : 0;
    s[t] = own;
    __syncthreads();
    for (int d = 1; d < 256; d <<= 1) {
        int v = (t >= d) ? s[t - d] : 0;
        __syncthreads();
        s[t] += v;
        __syncthreads();
    }
    if (t < SCAN_NB) bex[t] = s[t] - own;   // exclusive
}

__global__ void k_expand(const int* __restrict__ deg, const int* __restrict__ bex,
                         int* __restrict__ offs) {
    __shared__ int s[256];
    int b = blockIdx.x, t = threadIdx.x;
    int i = b * 256 + t;
    int v = (i < NN) ? deg[i] : 0;
    s[t] = v;
    __syncthreads();
    for (int d = 1; d < 256; d <<= 1) {
        int a = (t >= d) ? s[t - d] : 0;
        __syncthreads();
        s[t] += a;
        __syncthreads();
    }
    int excl = s[t] - v + bex[b];
    if (i < NN) offs[i] = excl;
    if (i == NN - 1) offs[NN] = excl + v;
}

__global__ void k_scatter(const int* __restrict__ row, const int* __restrict__ col,
                          const int* __restrict__ offs, int* __restrict__ cursor,
                          int* __restrict__ csr_src) {
    int e = blockIdx.x * blockDim.x + threadIdx.x;
    if (e < NE) {
        int c = col[e];
        int pos = offs[c] + atomicAdd(&cursor[c], 1);
        csr_src[pos] = row[e];
    }
}

// ---------------- x = relu(nf @ Wi + bi), bf16 MFMA ----------------
// 64 rows x 64 cols per block, 4 waves; wave w owns rows w*16..w*16+15
// (4 col-tiles of 16). K chunks of 32 staged to LDS as bf16.
// A: a_s[row][k], stride 40 bf16 (80 B = 20 banks -> 2-way, free).
// W: staged TRANSPOSED w_s[c][k] so B-fragment is one ds_read_b128.

__global__ __launch_bounds__(256) void k_xgemm(const float* __restrict__ nf,
                                               const float* __restrict__ Wi,
                                               const float* __restrict__ bi,
                                               float* __restrict__ x) {
    __shared__ __align__(16) unsigned short a_s[64 * 40];
    __shared__ __align__(16) unsigned short w_s[64 * 40];
    int t = threadIdx.x;
    int lane = t & 63;
    int w = t >> 6;
    int quad = lane >> 4;
    int l15 = lane & 15;
    int n0 = blockIdx.x * 64;

    f32x4 acc[4];
#pragma unroll
    for (int ct = 0; ct < 4; ct++) acc[ct] = (f32x4){0.f, 0.f, 0.f, 0.f};

    for (int k0 = 0; k0 < FIN; k0 += 32) {
        __syncthreads();
        // stage A: 64 rows x 32 k (512 float4 loads, 2/thread)
#pragma unroll
        for (int p = 0; p < 2; p++) {
            int i = t + p * 256;
            int row = i >> 3;
            int k4 = (i & 7) * 4;
            int kk = k0 + k4;
            int n = n0 + row;
            float4 v = make_float4(0.f, 0.f, 0.f, 0.f);
            if (n < NN && kk < FIN)
                v = *(const float4*)&nf[(size_t)n * FIN + kk];
            unsigned short* d = &a_s[row * 40 + k4];
            d[0] = f2bf(v.x); d[1] = f2bf(v.y); d[2] = f2bf(v.z); d[3] = f2bf(v.w);
        }
        // stage W transposed: w_s[c][k] from Wi[k][c] (512 float4 loads, 2/thread)
#pragma unroll
        for (int p = 0; p < 2; p++) {
            int i = t + p * 256;
            int krow = i >> 4;
            int c4 = (i & 15) * 4;
            int kk = k0 + krow;
            float4 v = make_float4(0.f, 0.f, 0.f, 0.f);
            if (kk < FIN)
                v = *(const float4*)&Wi[(size_t)kk * 64 + c4];
            w_s[(c4 + 0) * 40 + krow] = f2bf(v.x);
            w_s[(c4 + 1) * 40 + krow] = f2bf(v.y);
            w_s[(c4 + 2) * 40 + krow] = f2bf(v.z);
            w_s[(c4 + 3) * 40 + krow] = f2bf(v.w);
        }
        __syncthreads();
        // A-frag: lane holds A[m=l15][k=quad*8+j]; B-frag: W[k=quad*8+j][c=ct*16+l15]
        bf16x8 af = *(const bf16x8*)&a_s[(w * 16 + l15) * 40 + quad * 8];
#pragma unroll
        for (int ct = 0; ct < 4; ct++) {
            bf16x8 bf = *(const bf16x8*)&w_s[(ct * 16 + l15) * 40 + quad * 8];
            acc[ct] = __builtin_amdgcn_mfma_f32_16x16x32_bf16(af, bf, acc[ct], 0, 0, 0);
        }
    }
    // D layout: row = quad*4 + r, col = l15 (per col-tile)
#pragma unroll
    for (int ct = 0; ct < 4; ct++) {
        int c = ct * 16 + l15;
        float bv = bi[c];
#pragma unroll
        for (int r = 0; r < 4; r++) {
            int n = n0 + w * 16 + quad * 4 + r;
            if (n < NN)
                x[(size_t)n * 64 + c] = fmaxf(acc[ct][r] + bv, 0.f);
        }
    }
}

// ---------------- QKV + kv row + teleport sums ----------------
// kv row: [0..127] Kf*dinv bf16, [128..191] V bf16 (unscaled).
// M0*dinv = (Kf*dinv) (x) V is formed on the fly in k_hop0.

__global__ __launch_bounds__(256) void k_qkv(const float* __restrict__ x,
    const float* __restrict__ Wq, const float* __restrict__ bq,
    const float* __restrict__ Wk, const float* __restrict__ bk,
    const float* __restrict__ Wv, const float* __restrict__ bv,
    const float* __restrict__ hopwise, const float* __restrict__ dinv,
    float* __restrict__ Qg, float* __restrict__ hid,
    unsigned char* __restrict__ kv0, float* __restrict__ tMK) {
    __shared__ float wq_s[64 * 64], wk_s[64 * 64], wv_s[64 * 32];
    __shared__ float bq_s[64], bk_s[64], bv_s[32];
    __shared__ float xs[4][8][64];
    __shared__ float tacc[576];
    int t = threadIdx.x;
    for (int i = t; i < 4096; i += 256) { wq_s[i] = Wq[i]; wk_s[i] = Wk[i]; }
    for (int i = t; i < 2048; i += 256) wv_s[i] = Wv[i];
    if (t < 64) { bq_s[t] = bq[t]; bk_s[t] = bk[t]; }
    if (t >= 64 && t < 96) bv_s[t - 64] = bv[t - 64];
    for (int i = t; i < 576; i += 256) tacc[i] = 0.f;
    __syncthreads();
    int lane = t & 63;
    int w = t >> 6;
    int h = lane >> 4;
    int vcol = lane & 31;
    float hw0 = hopwise[0];
    float tkp = 0.f;
    float tmp_[8];
#pragma unroll
    for (int j = 0; j < 8; j++) tmp_[j] = 0.f;
    int tiles = (NN + 31) >> 5;
    for (int tile = blockIdx.x; tile < tiles; tile += gridDim.x) {
        int n0 = tile * 32 + w * 8;
        __syncthreads();
#pragma unroll
        for (int u = 0; u < 8; u++) {
            int n = n0 + u;
            xs[w][u][lane] = (n < NN) ? x[(size_t)n * 64 + lane] : 0.f;
        }
        __syncthreads();
        float aq[8], ak[8], av[8];
#pragma unroll
        for (int u = 0; u < 8; u++) { aq[u] = 0.f; ak[u] = 0.f; av[u] = 0.f; }
        for (int f = 0; f < 64; f++) {
            float wqv = wq_s[f * 64 + lane];
            float wkv = wk_s[f * 64 + lane];
            float wvv = wv_s[f * 32 + vcol];
#pragma unroll
            for (int u = 0; u < 8; u++) {
                float xf = xs[w][u][f];
                aq[u] = fmaf(xf, wqv, aq[u]);
                ak[u] = fmaf(xf, wkv, ak[u]);
                av[u] = fmaf(xf, wvv, av[u]);
            }
        }
#pragma unroll
        for (int u = 0; u < 8; u++) {
            int n = n0 + u;
            float q = aq[u] + bq_s[lane];
            float k = ak[u] + bk_s[lane];
            float v = av[u] + bv_s[vcol];
            float Qv = q > 0.f ? 1.f + q : expf(q);   // 1 + elu
            float Kv = k > 0.f ? 1.f + k : expf(k);
            if (n < NN) {
                Qg[(size_t)n * 64 + lane] = Qv;
                // teleport sums (UNSCALED): tacc M needs Kv * V[h*8+j]
                float vj[8];
#pragma unroll
                for (int j = 0; j < 8; j++) vj[j] = __shfl(v, h * 8 + j, 64);
                tkp += Kv;
#pragma unroll
                for (int j = 0; j < 8; j++) tmp_[j] += Kv * vj[j];
                float dv = dinv[n];
                unsigned short* kvrow = (unsigned short*)(kv0 + (size_t)n * KVROW);
                kvrow[lane] = f2bf(Kv * dv);
                if (lane < 32) kvrow[64 + lane] = f2bf(v);
                if (lane < 32) hid[(size_t)n * 32 + lane] = v * hw0;
            }
        }
    }
#pragma unroll
    for (int j = 0; j < 8; j++) atomicAdd(&tacc[lane * 8 + j], tmp_[j]);
    atomicAdd(&tacc[512 + lane], tkp);
    __syncthreads();
    for (int i = t; i < 576; i += 256) atomicAdd(&tMK[i], tacc[i]);
}

// ---------------- hop 0: gather Kf/V, outer-product on the fly ----------------
// One wave per destination node. Lane l = (h=l>>4, i=l&15): accumulates
// K1[l] and M1[h,i,0..7]. V broadcast: 16-B load shared by all lanes of a head.

__global__ __launch_bounds__(256) void k_hop0(const unsigned char* __restrict__ kv0,
    const int* __restrict__ offs, const int* __restrict__ csr_src,
    const float* __restrict__ dinv, const float* __restrict__ Qg,
    const float* __restrict__ hopwise, const float* __restrict__ headwise,
    unsigned char* __restrict__ S1, float* __restrict__ hid) {
    int t = threadIdx.x;
    int lane = t & 63;
    int n = (blockIdx.x * 256 + t) >> 6;
    if (n >= NN) return;
    int h = lane >> 4;
    float e0 = expf(headwise[0 * 2 + 0]);
    float e1 = expf(headwise[1 * 2 + 0]);
    float e2 = expf(headwise[2 * 2 + 0]);
    float e3 = expf(headwise[3 * 2 + 0]);
    float esum = e0 + e1 + e2 + e3;
    float eh = (h == 0) ? e0 : ((h == 1) ? e1 : ((h == 2) ? e2 : e3));
    float gam = hopwise[1] * eh / esum;

    int hoff = 128 + h * 16;
    int o0 = offs[n], o1 = offs[n + 1];
    float kacc = 0.f;
    float4 m0 = make_float4(0.f, 0.f, 0.f, 0.f);
    float4 m1 = make_float4(0.f, 0.f, 0.f, 0.f);
    int e = o0;
    for (; e + 1 < o1; e += 2) {
        int sa = csr_src[e];
        int sb = csr_src[e + 1];
        const unsigned char* ra = kv0 + (size_t)sa * KVROW;
        const unsigned char* rb = kv0 + (size_t)sb * KVROW;
        float ka = bf_lo(((const unsigned short*)ra)[lane]);
        uint4 va = *(const uint4*)(ra + hoff);
        float kb = bf_lo(((const unsigned short*)rb)[lane]);
        uint4 vb = *(const uint4*)(rb + hoff);
        kacc += ka;
        m0.x = fmaf(ka, bf_lo(va.x), m0.x); m0.y = fmaf(ka, bf_hi(va.x), m0.y);
        m0.z = fmaf(ka, bf_lo(va.y), m0.z); m0.w = fmaf(ka, bf_hi(va.y), m0.w);
        m1.x = fmaf(ka, bf_lo(va.z), m1.x); m1.y = fmaf(ka, bf_hi(va.z), m1.y);
        m1.z = fmaf(ka, bf_lo(va.w), m1.z); m1.w = fmaf(ka, bf_hi(va.w), m1.w);
        kacc += kb;
        m0.x = fmaf(kb, bf_lo(vb.x), m0.x); m0.y = fmaf(kb, bf_hi(vb.x), m0.y);
        m0.z = fmaf(kb, bf_lo(vb.y), m0.z); m0.w = fmaf(kb, bf_hi(vb.y), m0.w);
        m1.x = fmaf(kb, bf_lo(vb.z), m1.x); m1.y = fmaf(kb, bf_hi(vb.z), m1.y);
        m1.z = fmaf(kb, bf_lo(vb.w), m1.z); m1.w = fmaf(kb, bf_hi(vb.w), m1.w);
    }
    if (e < o1) {
        int sa = csr_src[e];
        const unsigned char* ra = kv0 + (size_t)sa * KVROW;
        float ka = bf_lo(((const unsigned short*)ra)[lane]);
        uint4 va = *(const uint4*)(ra + hoff);
        kacc += ka;
        m0.x = fmaf(ka, bf_lo(va.x), m0.x); m0.y = fmaf(ka, bf_hi(va.x), m0.y);
        m0.z = fmaf(ka, bf_lo(va.y), m0.z); m0.w = fmaf(ka, bf_hi(va.y), m0.w);
        m1.x = fmaf(ka, bf_lo(va.z), m1.x); m1.y = fmaf(ka, bf_hi(va.z), m1.y);
        m1.z = fmaf(ka, bf_lo(va.w), m1.w); m1.w = fmaf(ka, bf_hi(va.w), m1.w);
    }
    // write S1: K1 bf16 (*dinv), M1 fp8 (*dinv*16; 1/16 folded into hop-1 gamma)
    {
        float dv = dinv[n];
        float s16 = dv * 16.f;
        unsigned char* drow = S1 + (size_t)n * SROW;
        ((unsigned short*)drow)[lane] = f2bf(kacc * dv);
        unsigned u0 = __builtin_amdgcn_cvt_pk_fp8_f32(m0.x * s16, m0.y * s16, 0, false);
        u0 = __builtin_amdgcn_cvt_pk_fp8_f32(m0.z * s16, m0.w * s16, u0, true);
        unsigned u1 = __builtin_amdgcn_cvt_pk_fp8_f32(m1.x * s16, m1.y * s16, 0, false);
        u1 = __builtin_amdgcn_cvt_pk_fp8_f32(m1.z * s16, m1.w * s16, u1, true);
        uint2 pv; pv.x = u0; pv.y = u1;
        *(uint2*)(drow + 128 + lane * 8) = pv;
    }
    // attend (true-scale m, kacc)
    float qv = Qg[(size_t)n * 64 + lane];
    float hh[8];
    hh[0] = qv * m0.x; hh[1] = qv * m0.y; hh[2] = qv * m0.z; hh[3] = qv * m0.w;
    hh[4] = qv * m1.x; hh[5] = qv * m1.y; hh[6] = qv * m1.z; hh[7] = qv * m1.w;
    float cc = qv * kacc;
#pragma unroll
    for (int s = 1; s < 16; s <<= 1) {
#pragma unroll
        for (int j = 0; j < 8; j++) hh[j] += __shfl_xor(hh[j], s, 16);
        cc += __shfl_xor(cc, s, 16);
    }
    if ((lane & 15) < 8) {
        int j = lane & 7;
        float val = j < 4 ? (j < 2 ? (j == 0 ? hh[0] : hh[1]) : (j == 2 ? hh[2] : hh[3]))
                          : (j < 6 ? (j == 4 ? hh[4] : hh[5]) : (j == 6 ? hh[6] : hh[7]));
        size_t idx = (size_t)n * 32 + h * 8 + j;
        hid[idx] += gam * val / (cc + CSTF);
    }
}

// ---------------- hop 1: gather S1 (bf16 K + fp8 M), attend ----------------

__global__ __launch_bounds__(256) void k_prop1(const unsigned char* __restrict__ Sold,
    const int* __restrict__ offs, const int* __restrict__ csr_src,
    const float* __restrict__ Qg, const float* __restrict__ hopwise,
    const float* __restrict__ headwise, float* __restrict__ hid) {
    int t = threadIdx.x;
    int lane = t & 63;
    int n = (blockIdx.x * 256 + t) >> 6;
    if (n >= NN) return;
    int h = lane >> 4;
    float e0 = expf(headwise[0 * 2 + 1]);
    float e1 = expf(headwise[1 * 2 + 1]);
    float e2 = expf(headwise[2 * 2 + 1]);
    float e3 = expf(headwise[3 * 2 + 1]);
    float esum = e0 + e1 + e2 + e3;
    float eh = (h == 0) ? e0 : ((h == 1) ? e1 : ((h == 2) ? e2 : e3));
    // M carries an extra *16; fold 1/16 into gamma.
    float gam = hopwise[2] * eh / esum * 0.0625f;

    int o0 = offs[n], o1 = offs[n + 1];
    float kacc = 0.f;
    float4 m0 = make_float4(0.f, 0.f, 0.f, 0.f);
    float4 m1 = make_float4(0.f, 0.f, 0.f, 0.f);
    int e = o0;
    for (; e + 1 < o1; e += 2) {
        int sa = csr_src[e];
        int sb = csr_src[e + 1];
        const unsigned char* ra = Sold + (size_t)sa * SROW;
        const unsigned char* rb = Sold + (size_t)sb * SROW;
        float ka = bf_lo(((const unsigned short*)ra)[lane]);
        uint2 mva = *(const uint2*)(ra + 128 + lane * 8);
        float kb = bf_lo(((const unsigned short*)rb)[lane]);
        uint2 mvb = *(const uint2*)(rb + 128 + lane * 8);
        kacc += ka;
        {
            f32x2 a0 = __builtin_amdgcn_cvt_pk_f32_fp8(mva.x, false);
            f32x2 a1 = __builtin_amdgcn_cvt_pk_f32_fp8(mva.x, true);
            f32x2 b0 = __builtin_amdgcn_cvt_pk_f32_fp8(mva.y, false);
            f32x2 b1 = __builtin_amdgcn_cvt_pk_f32_fp8(mva.y, true);
            m0.x += a0.x; m0.y += a0.y; m0.z += a1.x; m0.w += a1.y;
            m1.x += b0.x; m1.y += b0.y; m1.z += b1.x; m1.w += b1.y;
        }
        kacc += kb;
        {
            f32x2 a0 = __builtin_amdgcn_cvt_pk_f32_fp8(mvb.x, false);
            f32x2 a1 = __builtin_amdgcn_cvt_pk_f32_fp8(mvb.x, true);
            f32x2 b0 = __builtin_amdgcn_cvt_pk_f32_fp8(mvb.y, false);
            f32x2 b1 = __builtin_amdgcn_cvt_pk_f32_fp8(mvb.y, true);
            m0.x += a0.x; m0.y += a0.y; m0.z += a1.x; m0.w += a1.y;
            m1.x += b0.x; m1.y += b0.y; m1.z += b1.x; m1.w += b1.y;
        }
    }
    if (e < o1) {
        int sa = csr_src[e];
        const unsigned char* ra = Sold + (size_t)sa * SROW;
        float ka = bf_lo(((const unsigned short*)ra)[lane]);
        uint2 mva = *(const uint2*)(ra + 128 + lane * 8);
        kacc += ka;
        f32x2 a0 = __builtin_amdgcn_cvt_pk_f32_fp8(mva.x, false);
        f32x2 a1 = __builtin_amdgcn_cvt_pk_f32_fp8(mva.x, true);
        f32x2 b0 = __builtin_amdgcn_cvt_pk_f32_fp8(mva.y, false);
        f32x2 b1 = __builtin_amdgcn_cvt_pk_f32_fp8(mva.y, true);
        m0.x += a0.x; m0.y += a0.y; m0.z += a1.x; m0.w += a1.y;
        m1.x += b0.x; m1.y += b0.y; m1.z += b1.x; m1.w += b1.y;
    }
    float qv = Qg[(size_t)n * 64 + lane];
    float hh[8];
    hh[0] = qv * m0.x; hh[1] = qv * m0.y; hh[2] = qv * m0.z; hh[3] = qv * m0.w;
    hh[4] = qv * m1.x; hh[5] = qv * m1.y; hh[6] = qv * m1.z; hh[7] = qv * m1.w;
    float cc = qv * kacc;
#pragma unroll
    for (int s = 1; s < 16; s <<= 1) {
#pragma unroll
        for (int j = 0; j < 8; j++) hh[j] += __shfl_xor(hh[j], s, 16);
        cc += __shfl_xor(cc, s, 16);
    }
    if ((lane & 15) < 8) {
        int j = lane & 7;
        float val = j < 4 ? (j < 2 ? (j == 0 ? hh[0] : hh[1]) : (j == 2 ? hh[2] : hh[3]))
                          : (j < 6 ? (j == 4 ? hh[4] : hh[5]) : (j == 6 ? hh[6] : hh[7]));
        size_t idx = (size_t)n * 32 + h * 8 + j;
        hid[idx] += gam * val / (cc + CSTF);
    }
}

// ---------------- final: out = hidden @ Wo + bo + teleport * teleportH ----------------

__global__ __launch_bounds__(256) void k_final(const float* __restrict__ hid,
    const float* __restrict__ Qg, const float* __restrict__ Wo,
    const float* __restrict__ bo, const float* __restrict__ tMK,
    const float* __restrict__ teleport, float* __restrict__ out) {
    __shared__ float tm[512];
    __shared__ float tk[64];
    __shared__ float wo[256];
    __shared__ float bos[8];
    int t = threadIdx.x;
    const float invN = 1.0f / (float)NN;
    for (int i = t; i < 512; i += 256) tm[i] = tMK[i] * invN;
    if (t < 64) tk[t] = tMK[512 + t] * invN;
    wo[t] = Wo[t & 255];
    if (t < 8) bos[t] = bo[t];
    __syncthreads();
    float tp = teleport[0];
    int lane = t & 63;
    int sub = lane & 7;
    int g = lane >> 3;
    int wid = (blockIdx.x * 256 + t) >> 6;
    int nwaves = gridDim.x * 4;
    for (int nb = wid * 8; nb < NN; nb += nwaves * 8) {
        int n = nb + g;
        if (n < NN) {
            const float* hrow = hid + (size_t)n * 32;
            const float* qrow = Qg + (size_t)n * 64;
            float o = bos[sub];
#pragma unroll
            for (int m = 0; m < 32; m++) o = fmaf(hrow[m], wo[m * 8 + sub], o);
            float th = 0.f;
#pragma unroll
            for (int h2 = 0; h2 < 4; h2++) {
                float num = 0.f, den = 0.f;
#pragma unroll
                for (int i = 0; i < 16; i++) {
                    float q = qrow[h2 * 16 + i];
                    num = fmaf(q, tm[h2 * 128 + i * 8 + sub], num);
                    den = fmaf(q, tk[h2 * 16 + i], den);
                }
                th += num / (den + CSTF);
            }
            out[(size_t)n * 8 + sub] = o + tp * th;
        }
    }
}

// ---------------- launch ----------------

extern "C" void kernel_launch(void* const* d_in, const int* in_sizes, int n_in,
                              void* d_out, int out_size, void* d_ws, size_t ws_size,
                              hipStream_t stream) {
    const float* nf = (const float*)d_in[0];
    const int* ei = (const int*)d_in[1];
    const float* Wi = (const float*)d_in[2];
    const float* bi = (const float*)d_in[3];
    const float* Wq = (const float*)d_in[4];
    const float* bq = (const float*)d_in[5];
    const float* Wk = (const float*)d_in[6];
    const float* bk = (const float*)d_in[7];
    const float* Wv = (const float*)d_in[8];
    const float* bv = (const float*)d_in[9];
    const float* Wo = (const float*)d_in[10];
    const float* bo = (const float*)d_in[11];
    const float* hopwise = (const float*)d_in[12];
    const float* headwise = (const float*)d_in[13];
    const float* teleport = (const float*)d_in[14];
    float* out = (float*)d_out;

    char* base = (char*)d_ws;
    size_t off = 0;
    auto alloc = [&](size_t bytes) -> void* {
        void* p = base + off;
        off = (off + bytes + 255) & ~(size_t)255;
        return p;
    };
    int* deg = (int*)alloc(NN * 4);
    int* cursor = (int*)alloc(NN * 4);
    int* offs = (int*)alloc((NN + 1) * 4);
    int* bsum = (int*)alloc(256 * 4);
    int* bex = (int*)alloc(256 * 4);
    float* dinv = (float*)alloc(NN * 4);
    int* csr_src = (int*)alloc((size_t)NE * 4);
    float* xbuf = (float*)alloc((size_t)NN * 64 * 4);
    float* Qg = (float*)alloc((size_t)NN * 64 * 4);
    float* hid = (float*)alloc((size_t)NN * 32 * 4);
    unsigned char* kv0 = (unsigned char*)alloc((size_t)NN * KVROW);
    unsigned char* S1 = (unsigned char*)alloc((size_t)NN * SROW);
    float* tMK = (float*)alloc(576 * 4);

    const int* rowp = ei;
    const int* colp = ei + NE;

    hipMemsetAsync(deg, 0, NN * 4, stream);
    hipMemsetAsync(tMK, 0, 576 * 4, stream);

    k_deg<<<(NE + 255) / 256, 256, 0, stream>>>(colp, deg);
    k_deginv<<<(NN + 255) / 256, 256, 0, stream>>>(deg, dinv, cursor);
    k_bsum<<<SCAN_NB, 256, 0, stream>>>(deg, bsum);
    k_bscan<<<1, 256, 0, stream>>>(bsum, bex);
    k_expand<<<SCAN_NB, 256, 0, stream>>>(deg, bex, offs);
    k_scatter<<<(NE + 255) / 256, 256, 0, stream>>>(rowp, colp, offs, cursor, csr_src);
    k_xgemm<<<(NN + 63) / 64, 256, 0, stream>>>(nf, Wi, bi, xbuf);
    k_qkv<<<512, 256, 0, stream>>>(xbuf, Wq, bq, Wk, bk, Wv, bv, hopwise, dinv,
                                   Qg, hid, kv0, tMK);
    k_hop0<<<(NN * 64 + 255) / 256, 256, 0, stream>>>(kv0, offs, csr_src, dinv, Qg,
                                                      hopwise, headwise, S1, hid);
    k_prop1<<<(NN * 64 + 255) / 256, 256, 0, stream>>>(S1, offs, csr_src, Qg,
                                                       hopwise, headwise, hid);
    k_final<<<1563, 256, 0, stream>>>(hid, Qg, Wo, bo, tMK, teleport, out);
}